// Round 3
// baseline (2126.045 us; speedup 1.0000x reference)
//
#include <hip/hip_runtime.h>

#define N_NODES  50000
#define NPAD     50048
#define N_EDGES  640000
#define IN_CH    64
#define EDGE_DIM 16
#define HID      128
#define HID2     256
#define NLAYER   5
#define NGRAPH   128

typedef unsigned short ushort_t;
typedef __attribute__((ext_vector_type(8))) short short8;
typedef __attribute__((ext_vector_type(4))) float f32x4;
typedef __attribute__((ext_vector_type(2))) float f32x2;

__device__ __forceinline__ float b2f(ushort_t u) {
    union { unsigned v; float f; } x; x.v = ((unsigned)u) << 16; return x.f;
}
__device__ __forceinline__ ushort_t f2b(float f) {
    union { float f; unsigned u; } x; x.f = f;
    unsigned u = x.u;
    unsigned r = (u + 0x7FFFu + ((u >> 16) & 1u)) >> 16;
    return (ushort_t)r;
}

// ---------------- prep: transpose + f32->bf16 convert ----------------
__global__ void k_transpose_cvt(const float* __restrict__ src, ushort_t* __restrict__ dst,
                                int B, int K, int Nn) {
    long total = (long)B * K * Nn;
    for (long i = (long)blockIdx.x * blockDim.x + threadIdx.x; i < total;
         i += (long)gridDim.x * blockDim.x) {
        int b = (int)(i / ((long)K * Nn));
        int rem = (int)(i - (long)b * K * Nn);
        int k = rem / Nn;
        int n = rem - k * Nn;
        dst[(long)b * K * Nn + (long)n * K + k] = f2b(src[i]);
    }
}

// W_l[k][j] = sum_i edge_w[k][i]*lin_w[l][i][j];  c_l[j] = sum_i edge_b[i]*lin_w[l][i][j] + lin_b[l][j]
__global__ __launch_bounds__(128) void k_combine(const float* __restrict__ ew,
                                                 const float* __restrict__ eb,
                                                 const float* __restrict__ lw,
                                                 const float* __restrict__ lb,
                                                 float* __restrict__ Wc, float* __restrict__ cc) {
    int l = blockIdx.x, j = threadIdx.x;
    float accW[EDGE_DIM];
#pragma unroll
    for (int k = 0; k < EDGE_DIM; ++k) accW[k] = 0.f;
    float accc = 0.f;
    for (int i = 0; i < HID; ++i) {
        float lwv = lw[((long)l * HID + i) * HID + j];
        accc = fmaf(eb[i], lwv, accc);
#pragma unroll
        for (int k = 0; k < EDGE_DIM; ++k)
            accW[k] = fmaf(ew[k * HID + i], lwv, accW[k]);
    }
#pragma unroll
    for (int k = 0; k < EDGE_DIM; ++k) Wc[(l * EDGE_DIM + k) * HID + j] = accW[k];
    cc[l * HID + j] = accc + lb[l * HID + j];
}

// ---------------- CSR build ----------------
__global__ __launch_bounds__(256) void k_hist(const int* __restrict__ ei, int* __restrict__ deg) {
    int e = blockIdx.x * 256 + threadIdx.x;
    if (e < N_EDGES) atomicAdd(&deg[ei[N_EDGES + e]], 1);
}

__global__ __launch_bounds__(1024) void k_scan1(const int* __restrict__ deg,
                                                int* __restrict__ offs, int* __restrict__ bsum) {
    __shared__ int s[1024];
    int i = blockIdx.x * 1024 + threadIdx.x;
    int v = (i < N_NODES) ? deg[i] : 0;
    s[threadIdx.x] = v;
    __syncthreads();
    for (int off = 1; off < 1024; off <<= 1) {
        int t = (threadIdx.x >= off) ? s[threadIdx.x - off] : 0;
        __syncthreads();
        s[threadIdx.x] += t;
        __syncthreads();
    }
    if (i < N_NODES) offs[i] = s[threadIdx.x] - v;  // exclusive
    if (threadIdx.x == 1023) bsum[blockIdx.x] = s[1023];
}

__global__ void k_scan2(int* __restrict__ bsum, int nb) {
    if (threadIdx.x == 0 && blockIdx.x == 0) {
        int acc = 0;
        for (int i = 0; i < nb; ++i) { int v = bsum[i]; bsum[i] = acc; acc += v; }
    }
}

__global__ __launch_bounds__(1024) void k_scan3(int* __restrict__ offs, const int* __restrict__ bsum) {
    int i = blockIdx.x * 1024 + threadIdx.x;
    if (i < N_NODES) offs[i] += bsum[blockIdx.x];
}

__global__ __launch_bounds__(256) void k_scatter(const int* __restrict__ ei,
                                                 const float* __restrict__ ea,
                                                 const int* __restrict__ offs,
                                                 int* __restrict__ cursor,
                                                 int* __restrict__ src_s,
                                                 float* __restrict__ ea_s) {
    int e = blockIdx.x * 256 + threadIdx.x;
    if (e >= N_EDGES) return;
    int d = ei[N_EDGES + e];
    int pos = offs[d] + atomicAdd(&cursor[d], 1);
    src_s[pos] = ei[e];
    const f32x4* srcp = (const f32x4*)(ea + (long)e * EDGE_DIM);
    f32x4* dst = (f32x4*)(ea_s + (long)pos * EDGE_DIM);
    dst[0] = srcp[0];
    dst[1] = srcp[1];
    dst[2] = srcp[2];
    dst[3] = srcp[3];
}

// ---------------- node encoder: h = relu(x @ node_w + node_b), f32 out ----------------
__global__ __launch_bounds__(256) void k_node_enc(const float* __restrict__ x,
                                                  const ushort_t* __restrict__ w0T,
                                                  const float* __restrict__ nb,
                                                  float* __restrict__ h) {
    int wv = threadIdx.x >> 6, l6 = threadIdx.x & 63;
    int lr = l6 & 15, lg = l6 >> 4;
    int grow = blockIdx.x * 64 + wv * 16 + lr;
    f32x4 acc[8];
#pragma unroll
    for (int nt = 0; nt < 8; ++nt) acc[nt] = (f32x4){0.f, 0.f, 0.f, 0.f};
#pragma unroll
    for (int kt = 0; kt < 2; ++kt) {
        int kk = kt * 32 + lg * 8;
        short8 a = {0, 0, 0, 0, 0, 0, 0, 0};
        if (grow < N_NODES) {
            const float* xr = x + (long)grow * IN_CH + kk;
            f32x4 v0 = *(const f32x4*)xr;
            f32x4 v1 = *(const f32x4*)(xr + 4);
#pragma unroll
            for (int j = 0; j < 4; ++j) { a[j] = (short)f2b(v0[j]); a[4 + j] = (short)f2b(v1[j]); }
        }
#pragma unroll
        for (int nt = 0; nt < 8; ++nt) {
            int brow = nt * 16 + lr;
            short8 b = *(const short8*)(w0T + brow * IN_CH + kk);
            acc[nt] = __builtin_amdgcn_mfma_f32_16x16x32_bf16(a, b, acc[nt], 0, 0, 0);
        }
    }
    int orow0 = blockIdx.x * 64 + wv * 16 + lg * 4;
#pragma unroll
    for (int nt = 0; nt < 8; ++nt) {
        int col = nt * 16 + lr;
        float bias = nb[col];
#pragma unroll
        for (int r = 0; r < 4; ++r) {
            int row = orow0 + r;
            if (row < N_NODES) h[(long)row * HID + col] = fmaxf(acc[nt][r] + bias, 0.f);
        }
    }
}

// ---------------- per-layer edge pass: z = (1+eps)*h + sum_{e->n} relu(h[src] + ea.W + c) ----------------
// 4 nodes/block, 1 wave(64)/node, 2 channels/thread, 4-deep gather pipeline.
__global__ __launch_bounds__(256) void k_edge(const float* __restrict__ Wc,
                                              const float* __restrict__ cc,
                                              const float* __restrict__ ea_s,
                                              const int* __restrict__ src_s,
                                              const int* __restrict__ offs,
                                              const int* __restrict__ deg,
                                              const float* __restrict__ h,
                                              const float* __restrict__ epsv,
                                              ushort_t* __restrict__ z, int l) {
    int lane = threadIdx.x & 63;
    int node = blockIdx.x * 4 + (threadIdx.x >> 6);
    if (node >= N_NODES) return;
    int ch0 = lane * 2;
    f32x2 w[EDGE_DIM];
#pragma unroll
    for (int k = 0; k < EDGE_DIM; ++k)
        w[k] = *(const f32x2*)(Wc + (l * EDGE_DIM + k) * HID + ch0);
    f32x2 cv = *(const f32x2*)(cc + l * HID + ch0);
    int s0 = offs[node];
    int dg = deg[node];
    float a0 = 0.f, a1 = 0.f;
    int i = 0;
    for (; i + 4 <= dg; i += 4) {
        int e = s0 + i;
        int sa = src_s[e], sb = src_s[e + 1], sc = src_s[e + 2], sd = src_s[e + 3];
        f32x2 ha = *(const f32x2*)(h + (long)sa * HID + ch0);
        f32x2 hb = *(const f32x2*)(h + (long)sb * HID + ch0);
        f32x2 hc = *(const f32x2*)(h + (long)sc * HID + ch0);
        f32x2 hd = *(const f32x2*)(h + (long)sd * HID + ch0);
#pragma unroll
        for (int j = 0; j < 4; ++j) {
            const f32x4* ep = (const f32x4*)(ea_s + (long)(e + j) * EDGE_DIM);
            f32x4 e0 = ep[0], e1 = ep[1], e2 = ep[2], e3 = ep[3];
            float q0 = cv[0], q1 = cv[1];
#pragma unroll
            for (int k = 0; k < 4; ++k) {
                q0 = fmaf(e0[k], w[k][0], q0);      q1 = fmaf(e0[k], w[k][1], q1);
            }
#pragma unroll
            for (int k = 0; k < 4; ++k) {
                q0 = fmaf(e1[k], w[4 + k][0], q0);  q1 = fmaf(e1[k], w[4 + k][1], q1);
            }
#pragma unroll
            for (int k = 0; k < 4; ++k) {
                q0 = fmaf(e2[k], w[8 + k][0], q0);  q1 = fmaf(e2[k], w[8 + k][1], q1);
            }
#pragma unroll
            for (int k = 0; k < 4; ++k) {
                q0 = fmaf(e3[k], w[12 + k][0], q0); q1 = fmaf(e3[k], w[12 + k][1], q1);
            }
            f32x2 hv = (j == 0) ? ha : (j == 1) ? hb : (j == 2) ? hc : hd;
            a0 += fmaxf(hv[0] + q0, 0.f);
            a1 += fmaxf(hv[1] + q1, 0.f);
        }
    }
    for (; i < dg; ++i) {
        int e = s0 + i;
        int s = src_s[e];
        f32x2 hv = *(const f32x2*)(h + (long)s * HID + ch0);
        const f32x4* ep = (const f32x4*)(ea_s + (long)e * EDGE_DIM);
        f32x4 e0 = ep[0], e1 = ep[1], e2 = ep[2], e3 = ep[3];
        float q0 = cv[0], q1 = cv[1];
#pragma unroll
        for (int k = 0; k < 4; ++k) {
            q0 = fmaf(e0[k], w[k][0], q0);      q1 = fmaf(e0[k], w[k][1], q1);
            q0 = fmaf(e1[k], w[4 + k][0], q0);  q1 = fmaf(e1[k], w[4 + k][1], q1);
            q0 = fmaf(e2[k], w[8 + k][0], q0);  q1 = fmaf(e2[k], w[8 + k][1], q1);
            q0 = fmaf(e3[k], w[12 + k][0], q0); q1 = fmaf(e3[k], w[12 + k][1], q1);
        }
        a0 += fmaxf(hv[0] + q0, 0.f);
        a1 += fmaxf(hv[1] + q1, 0.f);
    }
    float ep1 = 1.f + epsv[l];
    f32x2 hn = *(const f32x2*)(h + (long)node * HID + ch0);
    unsigned zz = (unsigned)f2b(fmaf(ep1, hn[0], a0)) |
                  ((unsigned)f2b(fmaf(ep1, hn[1], a1)) << 16);
    *(unsigned*)(z + (long)node * HID + ch0) = zz;
}

// ---------------- mlp1: I = relu(z @ mlp1_w + b1), bf16 out (B direct from global) ----------------
__global__ __launch_bounds__(256) void k_mlp1(const ushort_t* __restrict__ z,
                                              const ushort_t* __restrict__ w1T,
                                              const float* __restrict__ b1,
                                              ushort_t* __restrict__ ibuf, int l) {
    int wv = threadIdx.x >> 6, l6 = threadIdx.x & 63;
    int lr = l6 & 15, lg = l6 >> 4;
    int grow = blockIdx.x * 64 + wv * 16 + lr;
    const ushort_t* wl = w1T + (long)l * HID2 * HID;
    f32x4 acc[16];
#pragma unroll
    for (int nt = 0; nt < 16; ++nt) acc[nt] = (f32x4){0.f, 0.f, 0.f, 0.f};
    const ushort_t* zrow = z + (long)grow * HID;
#pragma unroll
    for (int kt = 0; kt < 4; ++kt) {
        int kk = kt * 32 + lg * 8;
        short8 a = *(const short8*)(zrow + kk);
#pragma unroll
        for (int nt = 0; nt < 16; ++nt) {
            short8 b = *(const short8*)(wl + (nt * 16 + lr) * HID + kk);
            acc[nt] = __builtin_amdgcn_mfma_f32_16x16x32_bf16(a, b, acc[nt], 0, 0, 0);
        }
    }
    int orow0 = blockIdx.x * 64 + wv * 16 + lg * 4;
#pragma unroll
    for (int nt = 0; nt < 16; ++nt) {
        int col = nt * 16 + lr;
        float bias = b1[l * HID2 + col];
#pragma unroll
        for (int r = 0; r < 4; ++r) {
            int row = orow0 + r;
            ibuf[(long)row * HID2 + col] = f2b(fmaxf(acc[nt][r] + bias, 0.f));
        }
    }
}

// ---------------- mlp2: z2 = I @ mlp2_w + b2 (f32 out) + BN partial sums ----------------
__global__ __launch_bounds__(256) void k_mlp2(const ushort_t* __restrict__ ibuf,
                                              const ushort_t* __restrict__ w2T,
                                              const float* __restrict__ b2,
                                              float* __restrict__ z2,
                                              float* __restrict__ bnstats, int l) {
    int wv = threadIdx.x >> 6, l6 = threadIdx.x & 63;
    int lr = l6 & 15, lg = l6 >> 4;
    int grow = blockIdx.x * 64 + wv * 16 + lr;
    const ushort_t* wl = w2T + (long)l * HID * HID2;
    f32x4 acc[8];
#pragma unroll
    for (int nt = 0; nt < 8; ++nt) acc[nt] = (f32x4){0.f, 0.f, 0.f, 0.f};
    const ushort_t* irow = ibuf + (long)grow * HID2;
#pragma unroll
    for (int kt = 0; kt < 8; ++kt) {
        int kk = kt * 32 + lg * 8;
        short8 a = *(const short8*)(irow + kk);
#pragma unroll
        for (int nt = 0; nt < 8; ++nt) {
            short8 b = *(const short8*)(wl + (nt * 16 + lr) * HID2 + kk);
            acc[nt] = __builtin_amdgcn_mfma_f32_16x16x32_bf16(a, b, acc[nt], 0, 0, 0);
        }
    }
    float* bnsum = bnstats + l * HID;
    float* bnssq = bnstats + (NLAYER + l) * HID;
    int orow0 = blockIdx.x * 64 + wv * 16 + lg * 4;
#pragma unroll
    for (int nt = 0; nt < 8; ++nt) {
        int col = nt * 16 + lr;
        float bias = b2[l * HID + col];
        float sv = 0.f, qv = 0.f;
#pragma unroll
        for (int r = 0; r < 4; ++r) {
            int row = orow0 + r;
            float v = acc[nt][r] + bias;
            if (row < N_NODES) {
                z2[(long)row * HID + col] = v;
                sv += v;
                qv += v * v;
            }
        }
        sv += __shfl_xor(sv, 16);
        sv += __shfl_xor(sv, 32);
        qv += __shfl_xor(qv, 16);
        qv += __shfl_xor(qv, 32);
        if (lg == 0) { atomicAdd(&bnsum[col], sv); atomicAdd(&bnssq[col], qv); }
    }
}

// ---------------- BN finalize ----------------
__global__ __launch_bounds__(128) void k_bnfin(const float* __restrict__ bnstats,
                                               const float* __restrict__ bng,
                                               const float* __restrict__ bnb,
                                               float* __restrict__ bnA, float* __restrict__ bnB,
                                               int l) {
    int c = threadIdx.x;
    float inv = 1.f / (float)N_NODES;
    float mu = bnstats[l * HID + c] * inv;
    float var = bnstats[(NLAYER + l) * HID + c] * inv - mu * mu;
    float rs = rsqrtf(var + 1e-5f);
    float a = rs * bng[l * HID + c];
    bnA[c] = a;
    bnB[c] = bnb[l * HID + c] - mu * a;
}

// ---------------- BN apply + residual + relu: h = relu(z2*A + B + h) ----------------
__global__ __launch_bounds__(1024) void k_resid(const float* __restrict__ z2,
                                                const float* __restrict__ bnA,
                                                const float* __restrict__ bnB,
                                                float* __restrict__ h) {
    long i = (long)blockIdx.x * 1024 + threadIdx.x;  // grid sized exactly N_NODES*HID
    int c = (int)(i & (HID - 1));
    float v = fmaf(z2[i], bnA[c], bnB[c]) + h[i];
    h[i] = fmaxf(v, 0.f);
}

// ---------------- pooling ----------------
__global__ void k_gstart(const int* __restrict__ batch, int* __restrict__ gstart) {
    int g = threadIdx.x;
    if (g > NGRAPH) return;
    int lo = 0, hi = N_NODES;
    while (lo < hi) { int mid = (lo + hi) >> 1; if (batch[mid] < g) lo = mid + 1; else hi = mid; }
    gstart[g] = lo;
}

__global__ __launch_bounds__(512) void k_pool(const float* __restrict__ h,
                                              const int* __restrict__ gstart,
                                              float* __restrict__ pooled,
                                              float* __restrict__ outp) {
    __shared__ float red[4][HID];
    int g = blockIdx.x;
    int ch = threadIdx.x & 127, seg = threadIdx.x >> 7;
    int st = gstart[g], en = gstart[g + 1];
    float s = 0.f;
    for (int i = st + seg; i < en; i += 4) s += h[(long)i * HID + ch];
    red[seg][ch] = s;
    __syncthreads();
    if (seg == 0) {
        float p = (red[0][ch] + red[1][ch] + red[2][ch] + red[3][ch]) /
                  fmaxf((float)(en - st), 1.f);
        pooled[g * HID + ch] = p;
        outp[g * HID + ch] = p;
    }
}

// ---------------- output MLP ----------------
__global__ __launch_bounds__(128) void k_outmlp(const float* __restrict__ pooled,
                                                const float* __restrict__ w1,
                                                const float* __restrict__ b1,
                                                const float* __restrict__ w2,
                                                const float* __restrict__ b2,
                                                float* __restrict__ outl) {
    __shared__ float pr[HID];
    __shared__ float hid[64];
    int g = blockIdx.x, t = threadIdx.x;
    pr[t] = pooled[g * HID + t];
    __syncthreads();
    if (t < 64) {
        float a = b1[t];
        for (int k = 0; k < HID; ++k) a = fmaf(pr[k], w1[k * 64 + t], a);
        hid[t] = fmaxf(a, 0.f);
    }
    __syncthreads();
    float a = b2[t];
#pragma unroll
    for (int j = 0; j < 64; ++j) a = fmaf(hid[j], w2[j * HID + t], a);
    outl[g * HID + t] = a;
}

// =====================================================================================
extern "C" void kernel_launch(void* const* d_in, const int* in_sizes, int n_in,
                              void* d_out, int out_size, void* d_ws, size_t ws_size,
                              hipStream_t stream) {
    (void)in_sizes; (void)n_in; (void)out_size; (void)ws_size;
    const float* x      = (const float*)d_in[0];
    const int*   ei     = (const int*)d_in[1];
    const float* ea     = (const float*)d_in[2];
    const int*   batch  = (const int*)d_in[3];
    const float* node_w = (const float*)d_in[4];
    const float* node_b = (const float*)d_in[5];
    const float* edge_w = (const float*)d_in[6];
    const float* edge_b = (const float*)d_in[7];
    const float* epsv   = (const float*)d_in[8];
    const float* lin_w  = (const float*)d_in[9];
    const float* lin_b  = (const float*)d_in[10];
    const float* m1w    = (const float*)d_in[11];
    const float* m1b    = (const float*)d_in[12];
    const float* m2w    = (const float*)d_in[13];
    const float* m2b    = (const float*)d_in[14];
    const float* bng    = (const float*)d_in[15];
    const float* bnb    = (const float*)d_in[16];
    const float* ow1    = (const float*)d_in[17];
    const float* ob1    = (const float*)d_in[18];
    const float* ow2    = (const float*)d_in[19];
    const float* ob2    = (const float*)d_in[20];

    char* ws = (char*)d_ws;
    size_t off = 0;
    auto alloc = [&](size_t bytes) -> char* {
        char* p = ws + off;
        off = (off + bytes + 255) & ~(size_t)255;
        return p;
    };
    float*    h       = (float*)alloc((size_t)NPAD * HID * 4);
    ushort_t* z       = (ushort_t*)alloc((size_t)NPAD * HID * 2);
    ushort_t* ibuf    = (ushort_t*)alloc((size_t)NPAD * HID2 * 2);
    float*    z2      = (float*)alloc((size_t)NPAD * HID * 4);
    float*    ea_s    = (float*)alloc((size_t)N_EDGES * EDGE_DIM * 4);
    int*      src_s   = (int*)alloc((size_t)N_EDGES * 4);
    int*      deg     = (int*)alloc((size_t)N_NODES * 4);
    int*      offs    = (int*)alloc((size_t)N_NODES * 4);
    int*      cursor  = (int*)alloc((size_t)N_NODES * 4);
    int*      bsum    = (int*)alloc(64 * 4);
    float*    Wc      = (float*)alloc((size_t)NLAYER * EDGE_DIM * HID * 4);
    float*    cc      = (float*)alloc((size_t)NLAYER * HID * 4);
    ushort_t* w0T     = (ushort_t*)alloc((size_t)HID * IN_CH * 2);
    ushort_t* w1T     = (ushort_t*)alloc((size_t)NLAYER * HID2 * HID * 2);
    ushort_t* w2T     = (ushort_t*)alloc((size_t)NLAYER * HID * HID2 * 2);
    float*    bnstats = (float*)alloc((size_t)2 * NLAYER * HID * 4);
    float*    bnA     = (float*)alloc(HID * 4);
    float*    bnB     = (float*)alloc(HID * 4);
    int*      gstart  = (int*)alloc((NGRAPH + 1) * 4);
    float*    pooled  = (float*)alloc((size_t)NGRAPH * HID * 4);

    hipMemsetAsync(deg, 0, (size_t)N_NODES * 4, stream);
    hipMemsetAsync(cursor, 0, (size_t)N_NODES * 4, stream);
    hipMemsetAsync(bnstats, 0, (size_t)2 * NLAYER * HID * 4, stream);

    k_transpose_cvt<<<64, 256, 0, stream>>>(node_w, w0T, 1, IN_CH, HID);
    k_transpose_cvt<<<640, 256, 0, stream>>>(m1w, w1T, NLAYER, HID, HID2);
    k_transpose_cvt<<<640, 256, 0, stream>>>(m2w, w2T, NLAYER, HID2, HID);
    k_combine<<<NLAYER, HID, 0, stream>>>(edge_w, edge_b, lin_w, lin_b, Wc, cc);

    k_hist<<<N_EDGES / 256, 256, 0, stream>>>(ei, deg);
    k_scan1<<<49, 1024, 0, stream>>>(deg, offs, bsum);
    k_scan2<<<1, 1, 0, stream>>>(bsum, 49);
    k_scan3<<<49, 1024, 0, stream>>>(offs, bsum);
    k_scatter<<<N_EDGES / 256, 256, 0, stream>>>(ei, ea, offs, cursor, src_s, ea_s);

    k_node_enc<<<NPAD / 64, 256, 0, stream>>>(x, w0T, node_b, h);

    for (int l = 0; l < NLAYER; ++l) {
        k_edge<<<(N_NODES + 3) / 4, 256, 0, stream>>>(Wc, cc, ea_s, src_s, offs, deg, h, epsv, z, l);
        k_mlp1<<<NPAD / 64, 256, 0, stream>>>(z, w1T, m1b, ibuf, l);
        k_mlp2<<<NPAD / 64, 256, 0, stream>>>(ibuf, w2T, m2b, z2, bnstats, l);
        k_bnfin<<<1, HID, 0, stream>>>(bnstats, bng, bnb, bnA, bnB, l);
        k_resid<<<(N_NODES * HID) / 1024, 1024, 0, stream>>>(z2, bnA, bnB, h);
    }

    k_gstart<<<1, 256, 0, stream>>>(batch, gstart);
    k_pool<<<NGRAPH, 512, 0, stream>>>(h, gstart, pooled, (float*)d_out + NGRAPH * HID);
    k_outmlp<<<NGRAPH, HID, 0, stream>>>(pooled, ow1, ob1, ow2, ob2, (float*)d_out);
}

// Round 4
// 1551.892 us; speedup vs baseline: 1.3700x; 1.3700x over previous
//
#include <hip/hip_runtime.h>

#define N_NODES  50000
#define NPAD     50048
#define N_EDGES  640000
#define IN_CH    64
#define EDGE_DIM 16
#define HID      128
#define HID2     256
#define NLAYER   5
#define NGRAPH   128
#define MTILES   (NPAD / 64)

typedef unsigned short ushort_t;
typedef __attribute__((ext_vector_type(8))) short short8;
typedef __attribute__((ext_vector_type(4))) float f32x4;
typedef __attribute__((ext_vector_type(2))) float f32x2;

__device__ __forceinline__ float b2f(ushort_t u) {
    union { unsigned v; float f; } x; x.v = ((unsigned)u) << 16; return x.f;
}
__device__ __forceinline__ ushort_t f2b(float f) {
    union { float f; unsigned u; } x; x.f = f;
    unsigned u = x.u;
    unsigned r = (u + 0x7FFFu + ((u >> 16) & 1u)) >> 16;
    return (ushort_t)r;
}

// ---------------- prep: transpose + f32->bf16 convert ----------------
__global__ void k_transpose_cvt(const float* __restrict__ src, ushort_t* __restrict__ dst,
                                int B, int K, int Nn) {
    long total = (long)B * K * Nn;
    for (long i = (long)blockIdx.x * blockDim.x + threadIdx.x; i < total;
         i += (long)gridDim.x * blockDim.x) {
        int b = (int)(i / ((long)K * Nn));
        int rem = (int)(i - (long)b * K * Nn);
        int k = rem / Nn;
        int n = rem - k * Nn;
        dst[(long)b * K * Nn + (long)n * K + k] = f2b(src[i]);
    }
}

// W_l[k][j] = sum_i edge_w[k][i]*lin_w[l][i][j];  c_l[j] = sum_i edge_b[i]*lin_w[l][i][j] + lin_b[l][j]
__global__ __launch_bounds__(128) void k_combine(const float* __restrict__ ew,
                                                 const float* __restrict__ eb,
                                                 const float* __restrict__ lw,
                                                 const float* __restrict__ lb,
                                                 float* __restrict__ Wc, float* __restrict__ cc) {
    int l = blockIdx.x, j = threadIdx.x;
    float accW[EDGE_DIM];
#pragma unroll
    for (int k = 0; k < EDGE_DIM; ++k) accW[k] = 0.f;
    float accc = 0.f;
    for (int i = 0; i < HID; ++i) {
        float lwv = lw[((long)l * HID + i) * HID + j];
        accc = fmaf(eb[i], lwv, accc);
#pragma unroll
        for (int k = 0; k < EDGE_DIM; ++k)
            accW[k] = fmaf(ew[k * HID + i], lwv, accW[k]);
    }
#pragma unroll
    for (int k = 0; k < EDGE_DIM; ++k) Wc[(l * EDGE_DIM + k) * HID + j] = accW[k];
    cc[l * HID + j] = accc + lb[l * HID + j];
}

// ---------------- CSR build ----------------
__global__ __launch_bounds__(256) void k_hist(const int* __restrict__ ei, int* __restrict__ deg) {
    int e = blockIdx.x * 256 + threadIdx.x;
    if (e < N_EDGES) atomicAdd(&deg[ei[N_EDGES + e]], 1);
}

__global__ __launch_bounds__(1024) void k_scan1(const int* __restrict__ deg,
                                                int* __restrict__ offs, int* __restrict__ bsum) {
    __shared__ int s[1024];
    int i = blockIdx.x * 1024 + threadIdx.x;
    int v = (i < N_NODES) ? deg[i] : 0;
    s[threadIdx.x] = v;
    __syncthreads();
    for (int off = 1; off < 1024; off <<= 1) {
        int t = (threadIdx.x >= off) ? s[threadIdx.x - off] : 0;
        __syncthreads();
        s[threadIdx.x] += t;
        __syncthreads();
    }
    if (i < N_NODES) offs[i] = s[threadIdx.x] - v;  // exclusive
    if (threadIdx.x == 1023) bsum[blockIdx.x] = s[1023];
}

__global__ void k_scan2(int* __restrict__ bsum, int nb) {
    if (threadIdx.x == 0 && blockIdx.x == 0) {
        int acc = 0;
        for (int i = 0; i < nb; ++i) { int v = bsum[i]; bsum[i] = acc; acc += v; }
    }
}

__global__ __launch_bounds__(1024) void k_scan3(int* __restrict__ offs, const int* __restrict__ bsum) {
    int i = blockIdx.x * 1024 + threadIdx.x;
    if (i < N_NODES) offs[i] += bsum[blockIdx.x];
}

__global__ __launch_bounds__(256) void k_scatter(const int* __restrict__ ei,
                                                 const float* __restrict__ ea,
                                                 const int* __restrict__ offs,
                                                 int* __restrict__ cursor,
                                                 int* __restrict__ src_s,
                                                 float* __restrict__ ea_s) {
    int e = blockIdx.x * 256 + threadIdx.x;
    if (e >= N_EDGES) return;
    int d = ei[N_EDGES + e];
    int pos = offs[d] + atomicAdd(&cursor[d], 1);
    src_s[pos] = ei[e];
    const f32x4* srcp = (const f32x4*)(ea + (long)e * EDGE_DIM);
    f32x4* dst = (f32x4*)(ea_s + (long)pos * EDGE_DIM);
    dst[0] = srcp[0];
    dst[1] = srcp[1];
    dst[2] = srcp[2];
    dst[3] = srcp[3];
}

// ---------------- node encoder: h = relu(x @ node_w + node_b), f32 out (LDS-staged B) --------
__global__ __launch_bounds__(256) void k_node_enc(const float* __restrict__ x,
                                                  const ushort_t* __restrict__ w0T,
                                                  const float* __restrict__ nb,
                                                  float* __restrict__ h) {
    __shared__ __align__(16) short lB[HID * IN_CH];  // 16KB [n=128][k=64], xor-swizzled
    for (int c = threadIdx.x; c < HID * IN_CH / 8; c += 256) {
        int row = c >> 3, k0 = (c & 7) * 8;
        short8 v = *(const short8*)(w0T + row * IN_CH + k0);
        int g = (k0 >> 3) ^ (row & 7);
        *(short8*)&lB[row * IN_CH + g * 8] = v;
    }
    __syncthreads();
    int wv = threadIdx.x >> 6, l6 = threadIdx.x & 63;
    int lr = l6 & 15, lg = l6 >> 4;
    int grow = blockIdx.x * 64 + wv * 16 + lr;
    f32x4 acc[8];
#pragma unroll
    for (int nt = 0; nt < 8; ++nt) acc[nt] = (f32x4){0.f, 0.f, 0.f, 0.f};
#pragma unroll
    for (int kt = 0; kt < 2; ++kt) {
        int kk = kt * 32 + lg * 8;
        short8 a = {0, 0, 0, 0, 0, 0, 0, 0};
        if (grow < N_NODES) {
            const float* xr = x + (long)grow * IN_CH + kk;
            f32x4 v0 = *(const f32x4*)xr;
            f32x4 v1 = *(const f32x4*)(xr + 4);
#pragma unroll
            for (int j = 0; j < 4; ++j) { a[j] = (short)f2b(v0[j]); a[4 + j] = (short)f2b(v1[j]); }
        }
#pragma unroll
        for (int nt = 0; nt < 8; ++nt) {
            int brow = nt * 16 + lr;
            short8 b = *(const short8*)&lB[brow * IN_CH + (((kk >> 3) ^ (brow & 7)) << 3)];
            acc[nt] = __builtin_amdgcn_mfma_f32_16x16x32_bf16(a, b, acc[nt], 0, 0, 0);
        }
    }
    int orow0 = blockIdx.x * 64 + wv * 16 + lg * 4;
#pragma unroll
    for (int nt = 0; nt < 8; ++nt) {
        int col = nt * 16 + lr;
        float bias = nb[col];
#pragma unroll
        for (int r = 0; r < 4; ++r) {
            int row = orow0 + r;
            if (row < N_NODES) h[(long)row * HID + col] = fmaxf(acc[nt][r] + bias, 0.f);
        }
    }
}

// ---------------- per-layer edge pass ----------------
__global__ __launch_bounds__(256) void k_edge(const float* __restrict__ Wc,
                                              const float* __restrict__ cc,
                                              const float* __restrict__ ea_s,
                                              const int* __restrict__ src_s,
                                              const int* __restrict__ offs,
                                              const int* __restrict__ deg,
                                              const float* __restrict__ h,
                                              const float* __restrict__ epsv,
                                              ushort_t* __restrict__ z, int l) {
    int lane = threadIdx.x & 63;
    int node = blockIdx.x * 4 + (threadIdx.x >> 6);
    if (node >= N_NODES) return;
    int ch0 = lane * 2;
    f32x2 w[EDGE_DIM];
#pragma unroll
    for (int k = 0; k < EDGE_DIM; ++k)
        w[k] = *(const f32x2*)(Wc + (l * EDGE_DIM + k) * HID + ch0);
    f32x2 cv = *(const f32x2*)(cc + l * HID + ch0);
    int s0 = offs[node];
    int dg = deg[node];
    float a0 = 0.f, a1 = 0.f;
    int i = 0;
    for (; i + 4 <= dg; i += 4) {
        int e = s0 + i;
        int sa = src_s[e], sb = src_s[e + 1], sc = src_s[e + 2], sd = src_s[e + 3];
        f32x2 ha = *(const f32x2*)(h + (long)sa * HID + ch0);
        f32x2 hb = *(const f32x2*)(h + (long)sb * HID + ch0);
        f32x2 hc = *(const f32x2*)(h + (long)sc * HID + ch0);
        f32x2 hd = *(const f32x2*)(h + (long)sd * HID + ch0);
#pragma unroll
        for (int j = 0; j < 4; ++j) {
            const f32x4* ep = (const f32x4*)(ea_s + (long)(e + j) * EDGE_DIM);
            f32x4 e0 = ep[0], e1 = ep[1], e2 = ep[2], e3 = ep[3];
            float q0 = cv[0], q1 = cv[1];
#pragma unroll
            for (int k = 0; k < 4; ++k) {
                q0 = fmaf(e0[k], w[k][0], q0);      q1 = fmaf(e0[k], w[k][1], q1);
            }
#pragma unroll
            for (int k = 0; k < 4; ++k) {
                q0 = fmaf(e1[k], w[4 + k][0], q0);  q1 = fmaf(e1[k], w[4 + k][1], q1);
            }
#pragma unroll
            for (int k = 0; k < 4; ++k) {
                q0 = fmaf(e2[k], w[8 + k][0], q0);  q1 = fmaf(e2[k], w[8 + k][1], q1);
            }
#pragma unroll
            for (int k = 0; k < 4; ++k) {
                q0 = fmaf(e3[k], w[12 + k][0], q0); q1 = fmaf(e3[k], w[12 + k][1], q1);
            }
            f32x2 hv = (j == 0) ? ha : (j == 1) ? hb : (j == 2) ? hc : hd;
            a0 += fmaxf(hv[0] + q0, 0.f);
            a1 += fmaxf(hv[1] + q1, 0.f);
        }
    }
    for (; i < dg; ++i) {
        int e = s0 + i;
        int s = src_s[e];
        f32x2 hv = *(const f32x2*)(h + (long)s * HID + ch0);
        const f32x4* ep = (const f32x4*)(ea_s + (long)e * EDGE_DIM);
        f32x4 e0 = ep[0], e1 = ep[1], e2 = ep[2], e3 = ep[3];
        float q0 = cv[0], q1 = cv[1];
#pragma unroll
        for (int k = 0; k < 4; ++k) {
            q0 = fmaf(e0[k], w[k][0], q0);      q1 = fmaf(e0[k], w[k][1], q1);
            q0 = fmaf(e1[k], w[4 + k][0], q0);  q1 = fmaf(e1[k], w[4 + k][1], q1);
            q0 = fmaf(e2[k], w[8 + k][0], q0);  q1 = fmaf(e2[k], w[8 + k][1], q1);
            q0 = fmaf(e3[k], w[12 + k][0], q0); q1 = fmaf(e3[k], w[12 + k][1], q1);
        }
        a0 += fmaxf(hv[0] + q0, 0.f);
        a1 += fmaxf(hv[1] + q1, 0.f);
    }
    float ep1 = 1.f + epsv[l];
    f32x2 hn = *(const f32x2*)(h + (long)node * HID + ch0);
    unsigned zz = (unsigned)f2b(fmaf(ep1, hn[0], a0)) |
                  ((unsigned)f2b(fmaf(ep1, hn[1], a1)) << 16);
    *(unsigned*)(z + (long)node * HID + ch0) = zz;
}

// ---------------- mlp1: persistent, N-split halves, 32KB LDS B ----------------
__global__ __launch_bounds__(256, 4) void k_mlp1(const ushort_t* __restrict__ z,
                                                 const ushort_t* __restrict__ w1T,
                                                 const float* __restrict__ b1,
                                                 ushort_t* __restrict__ ibuf, int l) {
    __shared__ __align__(16) short lB[128 * HID];  // 32KB [n-half=128][k=128]
    int half = blockIdx.x & 1;
    int mg = blockIdx.x >> 1;
    const ushort_t* wl = w1T + (long)l * HID2 * HID + (long)half * 128 * HID;
    for (int c = threadIdx.x; c < 128 * HID / 8; c += 256) {
        int row = c >> 4, k0 = (c & 15) * 8;
        short8 v = *(const short8*)(wl + row * HID + k0);
        int g = (k0 >> 3) ^ (row & 7);
        *(short8*)&lB[row * HID + g * 8] = v;
    }
    __syncthreads();
    int wv = threadIdx.x >> 6, l6 = threadIdx.x & 63;
    int lr = l6 & 15, lg = l6 >> 4;
    const float* b1l = b1 + l * HID2 + half * 128;
    for (int tile = mg; tile < MTILES; tile += 512) {
        int grow = tile * 64 + wv * 16 + lr;
        const ushort_t* zrow = z + (long)grow * HID;
        short8 a[4];
#pragma unroll
        for (int kt = 0; kt < 4; ++kt) a[kt] = *(const short8*)(zrow + kt * 32 + lg * 8);
        f32x4 acc[8];
#pragma unroll
        for (int nt = 0; nt < 8; ++nt) acc[nt] = (f32x4){0.f, 0.f, 0.f, 0.f};
#pragma unroll
        for (int kt = 0; kt < 4; ++kt) {
#pragma unroll
            for (int nt = 0; nt < 8; ++nt) {
                int brow = nt * 16 + lr;
                short8 b = *(const short8*)&lB[brow * HID + (((kt * 4 + lg) ^ (brow & 7)) << 3)];
                acc[nt] = __builtin_amdgcn_mfma_f32_16x16x32_bf16(a[kt], b, acc[nt], 0, 0, 0);
            }
        }
        int orow0 = tile * 64 + wv * 16 + lg * 4;
#pragma unroll
        for (int nt = 0; nt < 8; ++nt) {
            int col = half * 128 + nt * 16 + lr;
            float bias = b1l[nt * 16 + lr];
#pragma unroll
            for (int r = 0; r < 4; ++r)
                ibuf[(long)(orow0 + r) * HID2 + col] = f2b(fmaxf(acc[nt][r] + bias, 0.f));
        }
    }
}

// ---------------- mlp2: persistent, N-split halves, 32KB LDS B, bf16 z2 + reg BN stats ------
__global__ __launch_bounds__(256, 4) void k_mlp2(const ushort_t* __restrict__ ibuf,
                                                 const ushort_t* __restrict__ w2T,
                                                 const float* __restrict__ b2,
                                                 ushort_t* __restrict__ z2,
                                                 float* __restrict__ bnstats, int l) {
    __shared__ __align__(16) short lB[64 * HID2];  // 32KB [n-half=64][k=256]
    int half = blockIdx.x & 1;
    int mg = blockIdx.x >> 1;
    const ushort_t* wl = w2T + (long)l * HID * HID2 + (long)half * 64 * HID2;
    for (int c = threadIdx.x; c < 64 * HID2 / 8; c += 256) {
        int row = c >> 5, k0 = (c & 31) * 8;
        short8 v = *(const short8*)(wl + row * HID2 + k0);
        int g = (k0 >> 3) ^ (row & 7);
        *(short8*)&lB[row * HID2 + g * 8] = v;
    }
    __syncthreads();
    int wv = threadIdx.x >> 6, l6 = threadIdx.x & 63;
    int lr = l6 & 15, lg = l6 >> 4;
    float bS[4] = {0.f, 0.f, 0.f, 0.f}, bQ[4] = {0.f, 0.f, 0.f, 0.f};
    float bias[4];
#pragma unroll
    for (int nt = 0; nt < 4; ++nt) bias[nt] = b2[l * HID + half * 64 + nt * 16 + lr];
    for (int tile = mg; tile < MTILES; tile += 512) {
        int grow = tile * 64 + wv * 16 + lr;
        const ushort_t* irow = ibuf + (long)grow * HID2;
        short8 a[8];
#pragma unroll
        for (int kt = 0; kt < 8; ++kt) a[kt] = *(const short8*)(irow + kt * 32 + lg * 8);
        f32x4 acc[4];
#pragma unroll
        for (int nt = 0; nt < 4; ++nt) acc[nt] = (f32x4){0.f, 0.f, 0.f, 0.f};
#pragma unroll
        for (int kt = 0; kt < 8; ++kt) {
#pragma unroll
            for (int nt = 0; nt < 4; ++nt) {
                int brow = nt * 16 + lr;
                short8 b = *(const short8*)&lB[brow * HID2 + (((kt * 4 + lg) ^ (brow & 7)) << 3)];
                acc[nt] = __builtin_amdgcn_mfma_f32_16x16x32_bf16(a[kt], b, acc[nt], 0, 0, 0);
            }
        }
        int orow0 = tile * 64 + wv * 16 + lg * 4;
#pragma unroll
        for (int nt = 0; nt < 4; ++nt) {
            int col = half * 64 + nt * 16 + lr;
#pragma unroll
            for (int r = 0; r < 4; ++r) {
                int row = orow0 + r;
                float v = acc[nt][r] + bias[nt];
                if (row < N_NODES) {
                    z2[(long)row * HID + col] = f2b(v);
                    bS[nt] += v;
                    bQ[nt] += v * v;
                }
            }
        }
    }
#pragma unroll
    for (int nt = 0; nt < 4; ++nt) {
        float s = bS[nt], q = bQ[nt];
        s += __shfl_xor(s, 16); s += __shfl_xor(s, 32);
        q += __shfl_xor(q, 16); q += __shfl_xor(q, 32);
        if (lg == 0) {
            int col = half * 64 + nt * 16 + lr;
            atomicAdd(&bnstats[l * HID + col], s);
            atomicAdd(&bnstats[(NLAYER + l) * HID + col], q);
        }
    }
}

// ---------------- BN apply (stats->scale/shift inline) + residual + relu ----------------
__global__ __launch_bounds__(1024) void k_resid(const ushort_t* __restrict__ z2,
                                                const float* __restrict__ bnstats,
                                                const float* __restrict__ bng,
                                                const float* __restrict__ bnb,
                                                float* __restrict__ h, int l) {
    long i = (long)blockIdx.x * 1024 + threadIdx.x;  // grid covers N_NODES*HID exactly
    int c = (int)(i & (HID - 1));
    float inv = 1.f / (float)N_NODES;
    float mu = bnstats[l * HID + c] * inv;
    float var = bnstats[(NLAYER + l) * HID + c] * inv - mu * mu;
    float A = rsqrtf(var + 1e-5f) * bng[l * HID + c];
    float B = bnb[l * HID + c] - mu * A;
    float v = fmaf(b2f(z2[i]), A, B) + h[i];
    h[i] = fmaxf(v, 0.f);
}

// ---------------- pooling ----------------
__global__ void k_gstart(const int* __restrict__ batch, int* __restrict__ gstart) {
    int g = threadIdx.x;
    if (g > NGRAPH) return;
    int lo = 0, hi = N_NODES;
    while (lo < hi) { int mid = (lo + hi) >> 1; if (batch[mid] < g) lo = mid + 1; else hi = mid; }
    gstart[g] = lo;
}

__global__ __launch_bounds__(512) void k_pool(const float* __restrict__ h,
                                              const int* __restrict__ gstart,
                                              float* __restrict__ pooled,
                                              float* __restrict__ outp) {
    __shared__ float red[4][HID];
    int g = blockIdx.x;
    int ch = threadIdx.x & 127, seg = threadIdx.x >> 7;
    int st = gstart[g], en = gstart[g + 1];
    float s = 0.f;
    for (int i = st + seg; i < en; i += 4) s += h[(long)i * HID + ch];
    red[seg][ch] = s;
    __syncthreads();
    if (seg == 0) {
        float p = (red[0][ch] + red[1][ch] + red[2][ch] + red[3][ch]) /
                  fmaxf((float)(en - st), 1.f);
        pooled[g * HID + ch] = p;
        outp[g * HID + ch] = p;
    }
}

// ---------------- output MLP ----------------
__global__ __launch_bounds__(128) void k_outmlp(const float* __restrict__ pooled,
                                                const float* __restrict__ w1,
                                                const float* __restrict__ b1,
                                                const float* __restrict__ w2,
                                                const float* __restrict__ b2,
                                                float* __restrict__ outl) {
    __shared__ float pr[HID];
    __shared__ float hid[64];
    int g = blockIdx.x, t = threadIdx.x;
    pr[t] = pooled[g * HID + t];
    __syncthreads();
    if (t < 64) {
        float a = b1[t];
        for (int k = 0; k < HID; ++k) a = fmaf(pr[k], w1[k * 64 + t], a);
        hid[t] = fmaxf(a, 0.f);
    }
    __syncthreads();
    float a = b2[t];
#pragma unroll
    for (int j = 0; j < 64; ++j) a = fmaf(hid[j], w2[j * HID + t], a);
    outl[g * HID + t] = a;
}

// =====================================================================================
extern "C" void kernel_launch(void* const* d_in, const int* in_sizes, int n_in,
                              void* d_out, int out_size, void* d_ws, size_t ws_size,
                              hipStream_t stream) {
    (void)in_sizes; (void)n_in; (void)out_size; (void)ws_size;
    const float* x      = (const float*)d_in[0];
    const int*   ei     = (const int*)d_in[1];
    const float* ea     = (const float*)d_in[2];
    const int*   batch  = (const int*)d_in[3];
    const float* node_w = (const float*)d_in[4];
    const float* node_b = (const float*)d_in[5];
    const float* edge_w = (const float*)d_in[6];
    const float* edge_b = (const float*)d_in[7];
    const float* epsv   = (const float*)d_in[8];
    const float* lin_w  = (const float*)d_in[9];
    const float* lin_b  = (const float*)d_in[10];
    const float* m1w    = (const float*)d_in[11];
    const float* m1b    = (const float*)d_in[12];
    const float* m2w    = (const float*)d_in[13];
    const float* m2b    = (const float*)d_in[14];
    const float* bng    = (const float*)d_in[15];
    const float* bnb    = (const float*)d_in[16];
    const float* ow1    = (const float*)d_in[17];
    const float* ob1    = (const float*)d_in[18];
    const float* ow2    = (const float*)d_in[19];
    const float* ob2    = (const float*)d_in[20];

    char* ws = (char*)d_ws;
    size_t off = 0;
    auto alloc = [&](size_t bytes) -> char* {
        char* p = ws + off;
        off = (off + bytes + 255) & ~(size_t)255;
        return p;
    };
    float*    h       = (float*)alloc((size_t)NPAD * HID * 4);
    ushort_t* z       = (ushort_t*)alloc((size_t)NPAD * HID * 2);
    ushort_t* ibuf    = (ushort_t*)alloc((size_t)NPAD * HID2 * 2);
    ushort_t* z2      = (ushort_t*)alloc((size_t)NPAD * HID * 2);
    float*    ea_s    = (float*)alloc((size_t)N_EDGES * EDGE_DIM * 4);
    int*      src_s   = (int*)alloc((size_t)N_EDGES * 4);
    int*      deg     = (int*)alloc((size_t)N_NODES * 4);
    int*      offs    = (int*)alloc((size_t)N_NODES * 4);
    int*      cursor  = (int*)alloc((size_t)N_NODES * 4);
    int*      bsum    = (int*)alloc(64 * 4);
    float*    Wc      = (float*)alloc((size_t)NLAYER * EDGE_DIM * HID * 4);
    float*    cc      = (float*)alloc((size_t)NLAYER * HID * 4);
    ushort_t* w0T     = (ushort_t*)alloc((size_t)HID * IN_CH * 2);
    ushort_t* w1T     = (ushort_t*)alloc((size_t)NLAYER * HID2 * HID * 2);
    ushort_t* w2T     = (ushort_t*)alloc((size_t)NLAYER * HID * HID2 * 2);
    float*    bnstats = (float*)alloc((size_t)2 * NLAYER * HID * 4);
    int*      gstart  = (int*)alloc((NGRAPH + 1) * 4);
    float*    pooled  = (float*)alloc((size_t)NGRAPH * HID * 4);

    hipMemsetAsync(deg, 0, (size_t)N_NODES * 4, stream);
    hipMemsetAsync(cursor, 0, (size_t)N_NODES * 4, stream);
    hipMemsetAsync(bnstats, 0, (size_t)2 * NLAYER * HID * 4, stream);

    k_transpose_cvt<<<64, 256, 0, stream>>>(node_w, w0T, 1, IN_CH, HID);
    k_transpose_cvt<<<640, 256, 0, stream>>>(m1w, w1T, NLAYER, HID, HID2);
    k_transpose_cvt<<<640, 256, 0, stream>>>(m2w, w2T, NLAYER, HID2, HID);
    k_combine<<<NLAYER, HID, 0, stream>>>(edge_w, edge_b, lin_w, lin_b, Wc, cc);

    k_hist<<<N_EDGES / 256, 256, 0, stream>>>(ei, deg);
    k_scan1<<<49, 1024, 0, stream>>>(deg, offs, bsum);
    k_scan2<<<1, 1, 0, stream>>>(bsum, 49);
    k_scan3<<<49, 1024, 0, stream>>>(offs, bsum);
    k_scatter<<<N_EDGES / 256, 256, 0, stream>>>(ei, ea, offs, cursor, src_s, ea_s);

    k_node_enc<<<NPAD / 64, 256, 0, stream>>>(x, w0T, node_b, h);

    for (int l = 0; l < NLAYER; ++l) {
        k_edge<<<(N_NODES + 3) / 4, 256, 0, stream>>>(Wc, cc, ea_s, src_s, offs, deg, h, epsv, z, l);
        k_mlp1<<<1024, 256, 0, stream>>>(z, w1T, m1b, ibuf, l);
        k_mlp2<<<1024, 256, 0, stream>>>(ibuf, w2T, m2b, z2, bnstats, l);
        k_resid<<<(N_NODES * HID) / 1024, 1024, 0, stream>>>(z2, bnstats, bng, bnb, h, l);
    }

    k_gstart<<<1, 256, 0, stream>>>(batch, gstart);
    k_pool<<<NGRAPH, 512, 0, stream>>>(h, gstart, pooled, (float*)d_out + NGRAPH * HID);
    k_outmlp<<<NGRAPH, HID, 0, stream>>>(pooled, ow1, ob1, ow2, ob2, (float*)d_out);
}

// Round 7
// 1504.615 us; speedup vs baseline: 1.4130x; 1.0314x over previous
//
#include <hip/hip_runtime.h>

#define N_NODES  50000
#define NPAD     50048
#define N_EDGES  640000
#define IN_CH    64
#define EDGE_DIM 16
#define HID      128
#define HID2     256
#define NLAYER   5
#define NGRAPH   128
#define MTILES   (NPAD / 64)

typedef unsigned short ushort_t;
typedef __attribute__((ext_vector_type(8))) short short8;
typedef __attribute__((ext_vector_type(4))) short s16x4;
typedef __attribute__((ext_vector_type(4))) float f32x4;
typedef __attribute__((ext_vector_type(2))) float f32x2;

__device__ __forceinline__ float b2f(ushort_t u) {
    union { unsigned v; float f; } x; x.v = ((unsigned)u) << 16; return x.f;
}
__device__ __forceinline__ ushort_t f2b(float f) {
    union { float f; unsigned u; } x; x.f = f;
    unsigned u = x.u;
    unsigned r = (u + 0x7FFFu + ((u >> 16) & 1u)) >> 16;
    return (ushort_t)r;
}

// ---------------- prep: transpose + f32->bf16 convert ----------------
__global__ void k_transpose_cvt(const float* __restrict__ src, ushort_t* __restrict__ dst,
                                int B, int K, int Nn) {
    long total = (long)B * K * Nn;
    for (long i = (long)blockIdx.x * blockDim.x + threadIdx.x; i < total;
         i += (long)gridDim.x * blockDim.x) {
        int b = (int)(i / ((long)K * Nn));
        int rem = (int)(i - (long)b * K * Nn);
        int k = rem / Nn;
        int n = rem - k * Nn;
        dst[(long)b * K * Nn + (long)n * K + k] = f2b(src[i]);
    }
}

// WcbT bf16 [l][col=128][k=32 zero-padded] + cc f32
__global__ __launch_bounds__(128) void k_combine(const float* __restrict__ ew,
                                                 const float* __restrict__ eb,
                                                 const float* __restrict__ lw,
                                                 const float* __restrict__ lb,
                                                 ushort_t* __restrict__ WcbT,
                                                 float* __restrict__ cc) {
    int l = blockIdx.x, j = threadIdx.x;  // j = output channel (col)
    float accW[EDGE_DIM];
#pragma unroll
    for (int k = 0; k < EDGE_DIM; ++k) accW[k] = 0.f;
    float accc = 0.f;
    for (int i = 0; i < HID; ++i) {
        float lwv = lw[((long)l * HID + i) * HID + j];
        accc = fmaf(eb[i], lwv, accc);
#pragma unroll
        for (int k = 0; k < EDGE_DIM; ++k)
            accW[k] = fmaf(ew[k * HID + i], lwv, accW[k]);
    }
    ushort_t* wp = WcbT + ((long)l * HID + j) * 32;
#pragma unroll
    for (int k = 0; k < EDGE_DIM; ++k) wp[k] = f2b(accW[k]);
#pragma unroll
    for (int k = EDGE_DIM; k < 32; ++k) wp[k] = 0;
    cc[l * HID + j] = accc + lb[l * HID + j];
}

// ---------------- CSR build ----------------
__global__ __launch_bounds__(256) void k_hist(const int* __restrict__ ei, int* __restrict__ deg) {
    int e = blockIdx.x * 256 + threadIdx.x;
    if (e < N_EDGES) atomicAdd(&deg[ei[N_EDGES + e]], 1);
}

__global__ __launch_bounds__(1024) void k_scan1(const int* __restrict__ deg,
                                                int* __restrict__ offs, int* __restrict__ bsum) {
    __shared__ int s[1024];
    int i = blockIdx.x * 1024 + threadIdx.x;
    int v = (i < N_NODES) ? deg[i] : 0;
    s[threadIdx.x] = v;
    __syncthreads();
    for (int off = 1; off < 1024; off <<= 1) {
        int t = (threadIdx.x >= off) ? s[threadIdx.x - off] : 0;
        __syncthreads();
        s[threadIdx.x] += t;
        __syncthreads();
    }
    if (i < N_NODES) offs[i] = s[threadIdx.x] - v;  // exclusive
    if (threadIdx.x == 1023) bsum[blockIdx.x] = s[1023];
}

__global__ void k_scan2(int* __restrict__ bsum, int nb) {
    if (threadIdx.x == 0 && blockIdx.x == 0) {
        int acc = 0;
        for (int i = 0; i < nb; ++i) { int v = bsum[i]; bsum[i] = acc; acc += v; }
    }
}

__global__ __launch_bounds__(1024) void k_scan3(int* __restrict__ offs, const int* __restrict__ bsum) {
    int i = blockIdx.x * 1024 + threadIdx.x;
    if (i < N_NODES) offs[i] += bsum[blockIdx.x];
}

__global__ __launch_bounds__(256) void k_scatter(const int* __restrict__ ei,
                                                 const float* __restrict__ ea,
                                                 const int* __restrict__ offs,
                                                 int* __restrict__ cursor,
                                                 int* __restrict__ src_s,
                                                 ushort_t* __restrict__ ea_sb) {
    int e = blockIdx.x * 256 + threadIdx.x;
    if (e >= N_EDGES) return;
    int d = ei[N_EDGES + e];
    int pos = offs[d] + atomicAdd(&cursor[d], 1);
    src_s[pos] = ei[e];
    const f32x4* srcp = (const f32x4*)(ea + (long)e * EDGE_DIM);
    f32x4 v0 = srcp[0], v1 = srcp[1], v2 = srcp[2], v3 = srcp[3];
    short8 o0, o1;
#pragma unroll
    for (int j = 0; j < 4; ++j) {
        o0[j] = (short)f2b(v0[j]); o0[4 + j] = (short)f2b(v1[j]);
        o1[j] = (short)f2b(v2[j]); o1[4 + j] = (short)f2b(v3[j]);
    }
    short8* dst = (short8*)(ea_sb + (long)pos * EDGE_DIM);
    dst[0] = o0;
    dst[1] = o1;
}

// ---------------- node encoder: h = relu(x @ node_w + node_b), f32 + bf16 out --------
__global__ __launch_bounds__(256) void k_node_enc(const float* __restrict__ x,
                                                  const ushort_t* __restrict__ w0T,
                                                  const float* __restrict__ nb,
                                                  float* __restrict__ h,
                                                  ushort_t* __restrict__ hb) {
    __shared__ __align__(16) short lB[HID * IN_CH];  // 16KB [n=128][k=64], xor-swizzled
    for (int c = threadIdx.x; c < HID * IN_CH / 8; c += 256) {
        int row = c >> 3, k0 = (c & 7) * 8;
        short8 v = *(const short8*)(w0T + row * IN_CH + k0);
        int g = (k0 >> 3) ^ (row & 7);
        *(short8*)&lB[row * IN_CH + g * 8] = v;
    }
    __syncthreads();
    int wv = threadIdx.x >> 6, l6 = threadIdx.x & 63;
    int lr = l6 & 15, lg = l6 >> 4;
    int grow = blockIdx.x * 64 + wv * 16 + lr;
    f32x4 acc[8];
#pragma unroll
    for (int nt = 0; nt < 8; ++nt) acc[nt] = (f32x4){0.f, 0.f, 0.f, 0.f};
#pragma unroll
    for (int kt = 0; kt < 2; ++kt) {
        int kk = kt * 32 + lg * 8;
        short8 a = {0, 0, 0, 0, 0, 0, 0, 0};
        if (grow < N_NODES) {
            const float* xr = x + (long)grow * IN_CH + kk;
            f32x4 v0 = *(const f32x4*)xr;
            f32x4 v1 = *(const f32x4*)(xr + 4);
#pragma unroll
            for (int j = 0; j < 4; ++j) { a[j] = (short)f2b(v0[j]); a[4 + j] = (short)f2b(v1[j]); }
        }
#pragma unroll
        for (int nt = 0; nt < 8; ++nt) {
            int brow = nt * 16 + lr;
            short8 b = *(const short8*)&lB[brow * IN_CH + (((kk >> 3) ^ (brow & 7)) << 3)];
            acc[nt] = __builtin_amdgcn_mfma_f32_16x16x32_bf16(a, b, acc[nt], 0, 0, 0);
        }
    }
    int orow0 = blockIdx.x * 64 + wv * 16 + lg * 4;
#pragma unroll
    for (int nt = 0; nt < 8; ++nt) {
        int col = nt * 16 + lr;
        float bias = nb[col];
#pragma unroll
        for (int r = 0; r < 4; ++r) {
            int row = orow0 + r;
            if (row < N_NODES) {
                float v = fmaxf(acc[nt][r] + bias, 0.f);
                h[(long)row * HID + col] = v;
                hb[(long)row * HID + col] = f2b(v);
            }
        }
    }
}

// ---------------- per-layer edge GEMM (chunk [ce0,ce1)): g[e-ce0][c] = ea_e.W_l + c_l ----
__global__ __launch_bounds__(256) void k_edgegemm(const ushort_t* __restrict__ ea_sb,
                                                  const ushort_t* __restrict__ WcbT,
                                                  const float* __restrict__ cc,
                                                  ushort_t* __restrict__ g, int l,
                                                  int ce0, int ce1) {
    int wv = threadIdx.x >> 6, l6 = threadIdx.x & 63;
    int lr = l6 & 15, lg = l6 >> 4;
    short8 af[8];
    f32x4 cv[8];
    const ushort_t* wp = WcbT + (long)l * HID * 32;
#pragma unroll
    for (int nt = 0; nt < 8; ++nt) {
        af[nt] = *(const short8*)(wp + (nt * 16 + lr) * 32 + lg * 8);
        cv[nt] = *(const f32x4*)(cc + l * HID + nt * 16 + lg * 4);
    }
    for (int it = 0; it < 4; ++it) {
        int e0 = ce0 + blockIdx.x * 256 + wv * 64 + it * 16;
        int e = e0 + lr;
        short8 b = {0, 0, 0, 0, 0, 0, 0, 0};
        if (e < ce1 && lg < 2) b = *(const short8*)(ea_sb + (long)e * EDGE_DIM + lg * 8);
        f32x4 acc[8];
#pragma unroll
        for (int nt = 0; nt < 8; ++nt) acc[nt] = (f32x4){0.f, 0.f, 0.f, 0.f};
#pragma unroll
        for (int nt = 0; nt < 8; ++nt)
            acc[nt] = __builtin_amdgcn_mfma_f32_16x16x32_bf16(af[nt], b, acc[nt], 0, 0, 0);
        if (e < ce1) {
            ushort_t* gp = g + (long)(e - ce0) * HID + lg * 4;
#pragma unroll
            for (int nt = 0; nt < 8; ++nt) {
                s16x4 o;
#pragma unroll
                for (int r = 0; r < 4; ++r) o[r] = (short)f2b(acc[nt][r] + cv[nt][r]);
                *(s16x4*)(gp + nt * 16) = o;
            }
        }
    }
}

// ---------------- per-layer aggregation over chunk [ce0,ce1) ----------------
// mode bit0 = first chunk, bit1 = last chunk. Non-last accumulate into zacc (f32);
// last adds (1+eps)*h and writes z (bf16).
__global__ __launch_bounds__(256) void k_edge2(const ushort_t* __restrict__ g,
                                               const int* __restrict__ src_s,
                                               const int* __restrict__ offs,
                                               const int* __restrict__ deg,
                                               const float* __restrict__ h,
                                               const ushort_t* __restrict__ hb,
                                               const float* __restrict__ epsv,
                                               float* __restrict__ zacc,
                                               ushort_t* __restrict__ z,
                                               int l, int ce0, int ce1, int mode) {
    int lane = threadIdx.x & 63;
    int node = blockIdx.x * 4 + (threadIdx.x >> 6);
    if (node >= N_NODES) return;
    bool first = mode & 1, last = (mode & 2) != 0;
    int ch0 = lane * 2;
    int s0 = offs[node];
    int dg = deg[node];
    int e_lo = max(s0, ce0);
    int e_hi = min(s0 + dg, ce1);
    if (e_lo >= e_hi && !first && !last) return;  // untouched middle chunk
    float a0 = 0.f, a1 = 0.f;
    int i = e_lo;
    for (; i + 4 <= e_hi; i += 4) {
        long eg = (long)(i - ce0);
        int sa = src_s[i], sb_ = src_s[i + 1], sc_ = src_s[i + 2], sd_ = src_s[i + 3];
        unsigned ga = *(const unsigned*)(g + eg * HID + ch0);
        unsigned gb = *(const unsigned*)(g + (eg + 1) * HID + ch0);
        unsigned gc = *(const unsigned*)(g + (eg + 2) * HID + ch0);
        unsigned gd = *(const unsigned*)(g + (eg + 3) * HID + ch0);
        unsigned ha = *(const unsigned*)(hb + (long)sa * HID + ch0);
        unsigned hbv = *(const unsigned*)(hb + (long)sb_ * HID + ch0);
        unsigned hc = *(const unsigned*)(hb + (long)sc_ * HID + ch0);
        unsigned hd = *(const unsigned*)(hb + (long)sd_ * HID + ch0);
        a0 += fmaxf(b2f((ushort_t)(ha & 0xffff)) + b2f((ushort_t)(ga & 0xffff)), 0.f);
        a1 += fmaxf(b2f((ushort_t)(ha >> 16)) + b2f((ushort_t)(ga >> 16)), 0.f);
        a0 += fmaxf(b2f((ushort_t)(hbv & 0xffff)) + b2f((ushort_t)(gb & 0xffff)), 0.f);
        a1 += fmaxf(b2f((ushort_t)(hbv >> 16)) + b2f((ushort_t)(gb >> 16)), 0.f);
        a0 += fmaxf(b2f((ushort_t)(hc & 0xffff)) + b2f((ushort_t)(gc & 0xffff)), 0.f);
        a1 += fmaxf(b2f((ushort_t)(hc >> 16)) + b2f((ushort_t)(gc >> 16)), 0.f);
        a0 += fmaxf(b2f((ushort_t)(hd & 0xffff)) + b2f((ushort_t)(gd & 0xffff)), 0.f);
        a1 += fmaxf(b2f((ushort_t)(hd >> 16)) + b2f((ushort_t)(gd >> 16)), 0.f);
    }
    for (; i < e_hi; ++i) {
        long eg = (long)(i - ce0);
        int s = src_s[i];
        unsigned gv = *(const unsigned*)(g + eg * HID + ch0);
        unsigned hv = *(const unsigned*)(hb + (long)s * HID + ch0);
        a0 += fmaxf(b2f((ushort_t)(hv & 0xffff)) + b2f((ushort_t)(gv & 0xffff)), 0.f);
        a1 += fmaxf(b2f((ushort_t)(hv >> 16)) + b2f((ushort_t)(gv >> 16)), 0.f);
    }
    if (!first) {
        f32x2 p = *(const f32x2*)(zacc + (long)node * HID + ch0);
        a0 += p[0]; a1 += p[1];
    }
    if (last) {
        float ep1 = 1.f + epsv[l];
        f32x2 hn = *(const f32x2*)(h + (long)node * HID + ch0);
        unsigned zz = (unsigned)f2b(fmaf(ep1, hn[0], a0)) |
                      ((unsigned)f2b(fmaf(ep1, hn[1], a1)) << 16);
        *(unsigned*)(z + (long)node * HID + ch0) = zz;
    } else {
        *(f32x2*)(zacc + (long)node * HID + ch0) = (f32x2){a0, a1};
    }
}

// ---------------- mlp1: persistent, N-split halves, 32KB LDS B ----------------
__global__ __launch_bounds__(256, 4) void k_mlp1(const ushort_t* __restrict__ z,
                                                 const ushort_t* __restrict__ w1T,
                                                 const float* __restrict__ b1,
                                                 ushort_t* __restrict__ ibuf, int l) {
    __shared__ __align__(16) short lB[128 * HID];  // 32KB [n-half=128][k=128]
    int half = blockIdx.x & 1;
    int mg = blockIdx.x >> 1;
    const ushort_t* wl = w1T + (long)l * HID2 * HID + (long)half * 128 * HID;
    for (int c = threadIdx.x; c < 128 * HID / 8; c += 256) {
        int row = c >> 4, k0 = (c & 15) * 8;
        short8 v = *(const short8*)(wl + row * HID + k0);
        int g = (k0 >> 3) ^ (row & 7);
        *(short8*)&lB[row * HID + g * 8] = v;
    }
    __syncthreads();
    int wv = threadIdx.x >> 6, l6 = threadIdx.x & 63;
    int lr = l6 & 15, lg = l6 >> 4;
    const float* b1l = b1 + l * HID2 + half * 128;
    for (int tile = mg; tile < MTILES; tile += 512) {
        int grow = tile * 64 + wv * 16 + lr;
        const ushort_t* zrow = z + (long)grow * HID;
        short8 a[4];
#pragma unroll
        for (int kt = 0; kt < 4; ++kt) a[kt] = *(const short8*)(zrow + kt * 32 + lg * 8);
        f32x4 acc[8];
#pragma unroll
        for (int nt = 0; nt < 8; ++nt) acc[nt] = (f32x4){0.f, 0.f, 0.f, 0.f};
#pragma unroll
        for (int kt = 0; kt < 4; ++kt) {
#pragma unroll
            for (int nt = 0; nt < 8; ++nt) {
                int brow = nt * 16 + lr;
                short8 b = *(const short8*)&lB[brow * HID + (((kt * 4 + lg) ^ (brow & 7)) << 3)];
                acc[nt] = __builtin_amdgcn_mfma_f32_16x16x32_bf16(a[kt], b, acc[nt], 0, 0, 0);
            }
        }
        int orow0 = tile * 64 + wv * 16 + lg * 4;
#pragma unroll
        for (int nt = 0; nt < 8; ++nt) {
            int col = half * 128 + nt * 16 + lr;
            float bias = b1l[nt * 16 + lr];
#pragma unroll
            for (int r = 0; r < 4; ++r)
                ibuf[(long)(orow0 + r) * HID2 + col] = f2b(fmaxf(acc[nt][r] + bias, 0.f));
        }
    }
}

// ---------------- mlp2: persistent, N-split halves, 32KB LDS B, bf16 z2 + reg BN stats ------
__global__ __launch_bounds__(256, 4) void k_mlp2(const ushort_t* __restrict__ ibuf,
                                                 const ushort_t* __restrict__ w2T,
                                                 const float* __restrict__ b2,
                                                 ushort_t* __restrict__ z2,
                                                 float* __restrict__ bnstats, int l) {
    __shared__ __align__(16) short lB[64 * HID2];  // 32KB [n-half=64][k=256]
    int half = blockIdx.x & 1;
    int mg = blockIdx.x >> 1;
    const ushort_t* wl = w2T + (long)l * HID * HID2 + (long)half * 64 * HID2;
    for (int c = threadIdx.x; c < 64 * HID2 / 8; c += 256) {
        int row = c >> 5, k0 = (c & 31) * 8;
        short8 v = *(const short8*)(wl + row * HID2 + k0);
        int g = (k0 >> 3) ^ (row & 7);
        *(short8*)&lB[row * HID2 + g * 8] = v;
    }
    __syncthreads();
    int wv = threadIdx.x >> 6, l6 = threadIdx.x & 63;
    int lr = l6 & 15, lg = l6 >> 4;
    float bS[4] = {0.f, 0.f, 0.f, 0.f}, bQ[4] = {0.f, 0.f, 0.f, 0.f};
    float bias[4];
#pragma unroll
    for (int nt = 0; nt < 4; ++nt) bias[nt] = b2[l * HID + half * 64 + nt * 16 + lr];
    for (int tile = mg; tile < MTILES; tile += 512) {
        int grow = tile * 64 + wv * 16 + lr;
        const ushort_t* irow = ibuf + (long)grow * HID2;
        short8 a[8];
#pragma unroll
        for (int kt = 0; kt < 8; ++kt) a[kt] = *(const short8*)(irow + kt * 32 + lg * 8);
        f32x4 acc[4];
#pragma unroll
        for (int nt = 0; nt < 4; ++nt) acc[nt] = (f32x4){0.f, 0.f, 0.f, 0.f};
#pragma unroll
        for (int kt = 0; kt < 8; ++kt) {
#pragma unroll
            for (int nt = 0; nt < 4; ++nt) {
                int brow = nt * 16 + lr;
                short8 b = *(const short8*)&lB[brow * HID2 + (((kt * 4 + lg) ^ (brow & 7)) << 3)];
                acc[nt] = __builtin_amdgcn_mfma_f32_16x16x32_bf16(a[kt], b, acc[nt], 0, 0, 0);
            }
        }
        int orow0 = tile * 64 + wv * 16 + lg * 4;
#pragma unroll
        for (int nt = 0; nt < 4; ++nt) {
            int col = half * 64 + nt * 16 + lr;
#pragma unroll
            for (int r = 0; r < 4; ++r) {
                int row = orow0 + r;
                float v = acc[nt][r] + bias[nt];
                if (row < N_NODES) {
                    z2[(long)row * HID + col] = f2b(v);
                    bS[nt] += v;
                    bQ[nt] += v * v;
                }
            }
        }
    }
#pragma unroll
    for (int nt = 0; nt < 4; ++nt) {
        float s = bS[nt], q = bQ[nt];
        s += __shfl_xor(s, 16); s += __shfl_xor(s, 32);
        q += __shfl_xor(q, 16); q += __shfl_xor(q, 32);
        if (lg == 0) {
            int col = half * 64 + nt * 16 + lr;
            atomicAdd(&bnstats[l * HID + col], s);
            atomicAdd(&bnstats[(NLAYER + l) * HID + col], q);
        }
    }
}

// ---------------- BN apply + residual + relu: h(f32,bf16) = relu(z2*A + B + h) -------
__global__ __launch_bounds__(1024) void k_resid(const ushort_t* __restrict__ z2,
                                                const float* __restrict__ bnstats,
                                                const float* __restrict__ bng,
                                                const float* __restrict__ bnb,
                                                float* __restrict__ h,
                                                ushort_t* __restrict__ hb, int l) {
    long i = (long)blockIdx.x * 1024 + threadIdx.x;  // grid covers N_NODES*HID exactly
    int c = (int)(i & (HID - 1));
    float inv = 1.f / (float)N_NODES;
    float mu = bnstats[l * HID + c] * inv;
    float var = bnstats[(NLAYER + l) * HID + c] * inv - mu * mu;
    float A = rsqrtf(var + 1e-5f) * bng[l * HID + c];
    float B = bnb[l * HID + c] - mu * A;
    float v = fmaf(b2f(z2[i]), A, B) + h[i];
    v = fmaxf(v, 0.f);
    h[i] = v;
    hb[i] = f2b(v);
}

// ---------------- pooling ----------------
__global__ void k_gstart(const int* __restrict__ batch, int* __restrict__ gstart) {
    int g = threadIdx.x;
    if (g > NGRAPH) return;
    int lo = 0, hi = N_NODES;
    while (lo < hi) { int mid = (lo + hi) >> 1; if (batch[mid] < g) lo = mid + 1; else hi = mid; }
    gstart[g] = lo;
}

__global__ __launch_bounds__(512) void k_pool(const float* __restrict__ h,
                                              const int* __restrict__ gstart,
                                              float* __restrict__ pooled,
                                              float* __restrict__ outp) {
    __shared__ float red[4][HID];
    int g = blockIdx.x;
    int ch = threadIdx.x & 127, seg = threadIdx.x >> 7;
    int st = gstart[g], en = gstart[g + 1];
    float s = 0.f;
    for (int i = st + seg; i < en; i += 4) s += h[(long)i * HID + ch];
    red[seg][ch] = s;
    __syncthreads();
    if (seg == 0) {
        float p = (red[0][ch] + red[1][ch] + red[2][ch] + red[3][ch]) /
                  fmaxf((float)(en - st), 1.f);
        pooled[g * HID + ch] = p;
        outp[g * HID + ch] = p;
    }
}

// ---------------- output MLP ----------------
__global__ __launch_bounds__(128) void k_outmlp(const float* __restrict__ pooled,
                                                const float* __restrict__ w1,
                                                const float* __restrict__ b1,
                                                const float* __restrict__ w2,
                                                const float* __restrict__ b2,
                                                float* __restrict__ outl) {
    __shared__ float pr[HID];
    __shared__ float hid[64];
    int g = blockIdx.x, t = threadIdx.x;
    pr[t] = pooled[g * HID + t];
    __syncthreads();
    if (t < 64) {
        float a = b1[t];
        for (int k = 0; k < HID; ++k) a = fmaf(pr[k], w1[k * 64 + t], a);
        hid[t] = fmaxf(a, 0.f);
    }
    __syncthreads();
    float a = b2[t];
#pragma unroll
    for (int j = 0; j < 64; ++j) a = fmaf(hid[j], w2[j * HID + t], a);
    outl[g * HID + t] = a;
}

// =====================================================================================
extern "C" void kernel_launch(void* const* d_in, const int* in_sizes, int n_in,
                              void* d_out, int out_size, void* d_ws, size_t ws_size,
                              hipStream_t stream) {
    (void)in_sizes; (void)n_in; (void)out_size;
    const float* x      = (const float*)d_in[0];
    const int*   ei     = (const int*)d_in[1];
    const float* ea     = (const float*)d_in[2];
    const int*   batch  = (const int*)d_in[3];
    const float* node_w = (const float*)d_in[4];
    const float* node_b = (const float*)d_in[5];
    const float* edge_w = (const float*)d_in[6];
    const float* edge_b = (const float*)d_in[7];
    const float* epsv   = (const float*)d_in[8];
    const float* lin_w  = (const float*)d_in[9];
    const float* lin_b  = (const float*)d_in[10];
    const float* m1w    = (const float*)d_in[11];
    const float* m1b    = (const float*)d_in[12];
    const float* m2w    = (const float*)d_in[13];
    const float* m2b    = (const float*)d_in[14];
    const float* bng    = (const float*)d_in[15];
    const float* bnb    = (const float*)d_in[16];
    const float* ow1    = (const float*)d_in[17];
    const float* ob1    = (const float*)d_in[18];
    const float* ow2    = (const float*)d_in[19];
    const float* ob2    = (const float*)d_in[20];

    // chunk count for the edge-message buffer g, chosen from ws_size (deterministic)
    const size_t MiB = 1024ull * 1024ull;
    int NC;
    if      (ws_size >= 275 * MiB) NC = 1;   // total ~253 MiB
    else if (ws_size >= 193 * MiB) NC = 2;   // total ~175 MiB
    else if (ws_size >= 152 * MiB) NC = 4;   // total ~136 MiB
    else                           NC = 8;   // total ~116 MiB
    int EC = (N_EDGES + NC - 1) / NC;        // edges per chunk

    char* ws = (char*)d_ws;
    size_t off = 0;
    auto alloc = [&](size_t bytes) -> char* {
        char* p = ws + off;
        off = (off + bytes + 255) & ~(size_t)255;
        return p;
    };
    float*    h       = (float*)alloc((size_t)NPAD * HID * 4);
    ushort_t* hb      = (ushort_t*)alloc((size_t)NPAD * HID * 2);
    ushort_t* z       = (ushort_t*)alloc((size_t)NPAD * HID * 2);   // also reused as z2
    ushort_t* ibuf    = (ushort_t*)alloc((size_t)NPAD * HID2 * 2);  // also aliased as zacc
    ushort_t* ea_sb   = (ushort_t*)alloc((size_t)N_EDGES * EDGE_DIM * 2 + 64);
    ushort_t* g       = (ushort_t*)alloc((size_t)EC * HID * 2);
    int*      src_s   = (int*)alloc((size_t)N_EDGES * 4);
    int*      deg     = (int*)alloc((size_t)N_NODES * 4);
    int*      offs    = (int*)alloc((size_t)N_NODES * 4);
    int*      cursor  = (int*)alloc((size_t)N_NODES * 4);
    int*      bsum    = (int*)alloc(64 * 4);
    ushort_t* WcbT    = (ushort_t*)alloc((size_t)NLAYER * HID * 32 * 2);
    float*    cc      = (float*)alloc((size_t)NLAYER * HID * 4);
    ushort_t* w0T     = (ushort_t*)alloc((size_t)HID * IN_CH * 2);
    ushort_t* w1T     = (ushort_t*)alloc((size_t)NLAYER * HID2 * HID * 2);
    ushort_t* w2T     = (ushort_t*)alloc((size_t)NLAYER * HID * HID2 * 2);
    float*    bnstats = (float*)alloc((size_t)2 * NLAYER * HID * 4);
    int*      gstart  = (int*)alloc((NGRAPH + 1) * 4);
    float*    pooled  = (float*)alloc((size_t)NGRAPH * HID * 4);
    float*    zacc    = (float*)ibuf;  // alias: ibuf (NPAD*512B) >= zacc (NPAD*512B)
    ushort_t* z2      = z;             // alias: z consumed by mlp1 before mlp2 writes

    (void)hipMemsetAsync(deg, 0, (size_t)N_NODES * 4, stream);
    (void)hipMemsetAsync(cursor, 0, (size_t)N_NODES * 4, stream);
    (void)hipMemsetAsync(bnstats, 0, (size_t)2 * NLAYER * HID * 4, stream);

    k_transpose_cvt<<<64, 256, 0, stream>>>(node_w, w0T, 1, IN_CH, HID);
    k_transpose_cvt<<<640, 256, 0, stream>>>(m1w, w1T, NLAYER, HID, HID2);
    k_transpose_cvt<<<640, 256, 0, stream>>>(m2w, w2T, NLAYER, HID2, HID);
    k_combine<<<NLAYER, HID, 0, stream>>>(edge_w, edge_b, lin_w, lin_b, WcbT, cc);

    k_hist<<<N_EDGES / 256, 256, 0, stream>>>(ei, deg);
    k_scan1<<<49, 1024, 0, stream>>>(deg, offs, bsum);
    k_scan2<<<1, 1, 0, stream>>>(bsum, 49);
    k_scan3<<<49, 1024, 0, stream>>>(offs, bsum);
    k_scatter<<<N_EDGES / 256, 256, 0, stream>>>(ei, ea, offs, cursor, src_s, ea_sb);

    k_node_enc<<<NPAD / 64, 256, 0, stream>>>(x, w0T, node_b, h, hb);

    for (int l = 0; l < NLAYER; ++l) {
        for (int c = 0; c < NC; ++c) {
            int ce0 = c * EC;
            int ce1 = (ce0 + EC < N_EDGES) ? (ce0 + EC) : N_EDGES;
            int nblk = (ce1 - ce0 + 255) / 256;
            int mode = (c == 0 ? 1 : 0) | (c == NC - 1 ? 2 : 0);
            k_edgegemm<<<nblk, 256, 0, stream>>>(ea_sb, WcbT, cc, g, l, ce0, ce1);
            k_edge2<<<(N_NODES + 3) / 4, 256, 0, stream>>>(g, src_s, offs, deg, h, hb,
                                                           epsv, zacc, z, l, ce0, ce1, mode);
        }
        k_mlp1<<<1024, 256, 0, stream>>>(z, w1T, m1b, ibuf, l);
        k_mlp2<<<1024, 256, 0, stream>>>(ibuf, w2T, m2b, z2, bnstats, l);
        k_resid<<<(N_NODES * HID) / 1024, 1024, 0, stream>>>(z2, bnstats, bng, bnb, h, hb, l);
    }

    k_gstart<<<1, 256, 0, stream>>>(batch, gstart);
    k_pool<<<NGRAPH, 512, 0, stream>>>(h, gstart, pooled, (float*)d_out + NGRAPH * HID);
    k_outmlp<<<NGRAPH, HID, 0, stream>>>(pooled, ow1, ob1, ow2, ob2, (float*)d_out);
}

// Round 8
// 1451.292 us; speedup vs baseline: 1.4649x; 1.0367x over previous
//
#include <hip/hip_runtime.h>

#define N_NODES  50000
#define NPAD     50048
#define N_EDGES  640000
#define IN_CH    64
#define EDGE_DIM 16
#define HID      128
#define HID2     256
#define NLAYER   5
#define NGRAPH   128
#define MTILES   (NPAD / 64)

typedef unsigned short ushort_t;
typedef __attribute__((ext_vector_type(8))) short short8;
typedef __attribute__((ext_vector_type(4))) short s16x4;
typedef __attribute__((ext_vector_type(4))) float f32x4;
typedef __attribute__((ext_vector_type(2))) float f32x2;

__device__ __forceinline__ float b2f(ushort_t u) {
    union { unsigned v; float f; } x; x.v = ((unsigned)u) << 16; return x.f;
}
__device__ __forceinline__ ushort_t f2b(float f) {
    union { float f; unsigned u; } x; x.f = f;
    unsigned u = x.u;
    unsigned r = (u + 0x7FFFu + ((u >> 16) & 1u)) >> 16;
    return (ushort_t)r;
}

// ---------------- prep: transpose + f32->bf16 convert ----------------
__global__ void k_transpose_cvt(const float* __restrict__ src, ushort_t* __restrict__ dst,
                                int B, int K, int Nn) {
    long total = (long)B * K * Nn;
    for (long i = (long)blockIdx.x * blockDim.x + threadIdx.x; i < total;
         i += (long)gridDim.x * blockDim.x) {
        int b = (int)(i / ((long)K * Nn));
        int rem = (int)(i - (long)b * K * Nn);
        int k = rem / Nn;
        int n = rem - k * Nn;
        dst[(long)b * K * Nn + (long)n * K + k] = f2b(src[i]);
    }
}

// WcbT bf16 [l][col=128][k=32 zero-padded] + cc f32
__global__ __launch_bounds__(128) void k_combine(const float* __restrict__ ew,
                                                 const float* __restrict__ eb,
                                                 const float* __restrict__ lw,
                                                 const float* __restrict__ lb,
                                                 ushort_t* __restrict__ WcbT,
                                                 float* __restrict__ cc) {
    int l = blockIdx.x, j = threadIdx.x;  // j = output channel (col)
    float accW[EDGE_DIM];
#pragma unroll
    for (int k = 0; k < EDGE_DIM; ++k) accW[k] = 0.f;
    float accc = 0.f;
    for (int i = 0; i < HID; ++i) {
        float lwv = lw[((long)l * HID + i) * HID + j];
        accc = fmaf(eb[i], lwv, accc);
#pragma unroll
        for (int k = 0; k < EDGE_DIM; ++k)
            accW[k] = fmaf(ew[k * HID + i], lwv, accW[k]);
    }
    ushort_t* wp = WcbT + ((long)l * HID + j) * 32;
#pragma unroll
    for (int k = 0; k < EDGE_DIM; ++k) wp[k] = f2b(accW[k]);
#pragma unroll
    for (int k = EDGE_DIM; k < 32; ++k) wp[k] = 0;
    cc[l * HID + j] = accc + lb[l * HID + j];
}

// ---------------- CSR build ----------------
__global__ __launch_bounds__(256) void k_hist(const int* __restrict__ ei, int* __restrict__ deg) {
    int e = blockIdx.x * 256 + threadIdx.x;
    if (e < N_EDGES) atomicAdd(&deg[ei[N_EDGES + e]], 1);
}

__global__ __launch_bounds__(1024) void k_scan1(const int* __restrict__ deg,
                                                int* __restrict__ offs, int* __restrict__ bsum) {
    __shared__ int s[1024];
    int i = blockIdx.x * 1024 + threadIdx.x;
    int v = (i < N_NODES) ? deg[i] : 0;
    s[threadIdx.x] = v;
    __syncthreads();
    for (int off = 1; off < 1024; off <<= 1) {
        int t = (threadIdx.x >= off) ? s[threadIdx.x - off] : 0;
        __syncthreads();
        s[threadIdx.x] += t;
        __syncthreads();
    }
    if (i < N_NODES) offs[i] = s[threadIdx.x] - v;  // exclusive
    if (threadIdx.x == 1023) bsum[blockIdx.x] = s[1023];
}

__global__ void k_scan2(int* __restrict__ bsum, int nb) {
    if (threadIdx.x == 0 && blockIdx.x == 0) {
        int acc = 0;
        for (int i = 0; i < nb; ++i) { int v = bsum[i]; bsum[i] = acc; acc += v; }
    }
}

__global__ __launch_bounds__(1024) void k_scan3(int* __restrict__ offs, const int* __restrict__ bsum) {
    int i = blockIdx.x * 1024 + threadIdx.x;
    if (i < N_NODES) offs[i] += bsum[blockIdx.x];
}

__global__ __launch_bounds__(256) void k_scatter(const int* __restrict__ ei,
                                                 const float* __restrict__ ea,
                                                 const int* __restrict__ offs,
                                                 int* __restrict__ cursor,
                                                 int* __restrict__ src_s,
                                                 ushort_t* __restrict__ ea_sb) {
    int e = blockIdx.x * 256 + threadIdx.x;
    if (e >= N_EDGES) return;
    int d = ei[N_EDGES + e];
    int pos = offs[d] + atomicAdd(&cursor[d], 1);
    src_s[pos] = ei[e];
    const f32x4* srcp = (const f32x4*)(ea + (long)e * EDGE_DIM);
    f32x4 v0 = srcp[0], v1 = srcp[1], v2 = srcp[2], v3 = srcp[3];
    short8 o0, o1;
#pragma unroll
    for (int j = 0; j < 4; ++j) {
        o0[j] = (short)f2b(v0[j]); o0[4 + j] = (short)f2b(v1[j]);
        o1[j] = (short)f2b(v2[j]); o1[4 + j] = (short)f2b(v3[j]);
    }
    short8* dst = (short8*)(ea_sb + (long)pos * EDGE_DIM);
    dst[0] = o0;
    dst[1] = o1;
}

// ---------------- node encoder: h = relu(x @ node_w + node_b), f32 + bf16 out --------
__global__ __launch_bounds__(256) void k_node_enc(const float* __restrict__ x,
                                                  const ushort_t* __restrict__ w0T,
                                                  const float* __restrict__ nb,
                                                  float* __restrict__ h,
                                                  ushort_t* __restrict__ hb) {
    __shared__ __align__(16) short lB[HID * IN_CH];  // 16KB [n=128][k=64], xor-swizzled
    for (int c = threadIdx.x; c < HID * IN_CH / 8; c += 256) {
        int row = c >> 3, k0 = (c & 7) * 8;
        short8 v = *(const short8*)(w0T + row * IN_CH + k0);
        int g = (k0 >> 3) ^ (row & 7);
        *(short8*)&lB[row * IN_CH + g * 8] = v;
    }
    __syncthreads();
    int wv = threadIdx.x >> 6, l6 = threadIdx.x & 63;
    int lr = l6 & 15, lg = l6 >> 4;
    int grow = blockIdx.x * 64 + wv * 16 + lr;
    f32x4 acc[8];
#pragma unroll
    for (int nt = 0; nt < 8; ++nt) acc[nt] = (f32x4){0.f, 0.f, 0.f, 0.f};
#pragma unroll
    for (int kt = 0; kt < 2; ++kt) {
        int kk = kt * 32 + lg * 8;
        short8 a = {0, 0, 0, 0, 0, 0, 0, 0};
        if (grow < N_NODES) {
            const float* xr = x + (long)grow * IN_CH + kk;
            f32x4 v0 = *(const f32x4*)xr;
            f32x4 v1 = *(const f32x4*)(xr + 4);
#pragma unroll
            for (int j = 0; j < 4; ++j) { a[j] = (short)f2b(v0[j]); a[4 + j] = (short)f2b(v1[j]); }
        }
#pragma unroll
        for (int nt = 0; nt < 8; ++nt) {
            int brow = nt * 16 + lr;
            short8 b = *(const short8*)&lB[brow * IN_CH + (((kk >> 3) ^ (brow & 7)) << 3)];
            acc[nt] = __builtin_amdgcn_mfma_f32_16x16x32_bf16(a, b, acc[nt], 0, 0, 0);
        }
    }
    int orow0 = blockIdx.x * 64 + wv * 16 + lg * 4;
#pragma unroll
    for (int nt = 0; nt < 8; ++nt) {
        int col = nt * 16 + lr;
        float bias = nb[col];
#pragma unroll
        for (int r = 0; r < 4; ++r) {
            int row = orow0 + r;
            if (row < N_NODES) {
                float v = fmaxf(acc[nt][r] + bias, 0.f);
                h[(long)row * HID + col] = v;
                hb[(long)row * HID + col] = f2b(v);
            }
        }
    }
}

// ---------------- per-layer edge GEMM (chunk [ce0,ce1)): g[e-ce0][c] = ea_e.W_l + c_l ----
__global__ __launch_bounds__(256) void k_edgegemm(const ushort_t* __restrict__ ea_sb,
                                                  const ushort_t* __restrict__ WcbT,
                                                  const float* __restrict__ cc,
                                                  ushort_t* __restrict__ g, int l,
                                                  int ce0, int ce1) {
    int wv = threadIdx.x >> 6, l6 = threadIdx.x & 63;
    int lr = l6 & 15, lg = l6 >> 4;
    short8 af[8];
    f32x4 cv[8];
    const ushort_t* wp = WcbT + (long)l * HID * 32;
#pragma unroll
    for (int nt = 0; nt < 8; ++nt) {
        af[nt] = *(const short8*)(wp + (nt * 16 + lr) * 32 + lg * 8);
        cv[nt] = *(const f32x4*)(cc + l * HID + nt * 16 + lg * 4);
    }
    for (int it = 0; it < 4; ++it) {
        int e0 = ce0 + blockIdx.x * 256 + wv * 64 + it * 16;
        int e = e0 + lr;
        short8 b = {0, 0, 0, 0, 0, 0, 0, 0};
        if (e < ce1 && lg < 2) b = *(const short8*)(ea_sb + (long)e * EDGE_DIM + lg * 8);
        f32x4 acc[8];
#pragma unroll
        for (int nt = 0; nt < 8; ++nt) acc[nt] = (f32x4){0.f, 0.f, 0.f, 0.f};
#pragma unroll
        for (int nt = 0; nt < 8; ++nt)
            acc[nt] = __builtin_amdgcn_mfma_f32_16x16x32_bf16(af[nt], b, acc[nt], 0, 0, 0);
        if (e < ce1) {
            ushort_t* gp = g + (long)(e - ce0) * HID + lg * 4;
#pragma unroll
            for (int nt = 0; nt < 8; ++nt) {
                s16x4 o;
#pragma unroll
                for (int r = 0; r < 4; ++r) o[r] = (short)f2b(acc[nt][r] + cv[nt][r]);
                *(s16x4*)(gp + nt * 16) = o;
            }
        }
    }
}

// ---------------- per-layer aggregation over chunk [ce0,ce1) ----------------
__global__ __launch_bounds__(256) void k_edge2(const ushort_t* __restrict__ g,
                                               const int* __restrict__ src_s,
                                               const int* __restrict__ offs,
                                               const int* __restrict__ deg,
                                               const float* __restrict__ h,
                                               const ushort_t* __restrict__ hb,
                                               const float* __restrict__ epsv,
                                               float* __restrict__ zacc,
                                               ushort_t* __restrict__ z,
                                               int l, int ce0, int ce1, int mode) {
    int lane = threadIdx.x & 63;
    int node = blockIdx.x * 4 + (threadIdx.x >> 6);
    if (node >= N_NODES) return;
    bool first = mode & 1, last = (mode & 2) != 0;
    int ch0 = lane * 2;
    int s0 = offs[node];
    int dg = deg[node];
    int e_lo = max(s0, ce0);
    int e_hi = min(s0 + dg, ce1);
    if (e_lo >= e_hi && !first && !last) return;  // untouched middle chunk
    float a0 = 0.f, a1 = 0.f;
    int i = e_lo;
    for (; i + 4 <= e_hi; i += 4) {
        long eg = (long)(i - ce0);
        int sa = src_s[i], sb_ = src_s[i + 1], sc_ = src_s[i + 2], sd_ = src_s[i + 3];
        unsigned ga = *(const unsigned*)(g + eg * HID + ch0);
        unsigned gb = *(const unsigned*)(g + (eg + 1) * HID + ch0);
        unsigned gc = *(const unsigned*)(g + (eg + 2) * HID + ch0);
        unsigned gd = *(const unsigned*)(g + (eg + 3) * HID + ch0);
        unsigned ha = *(const unsigned*)(hb + (long)sa * HID + ch0);
        unsigned hbv = *(const unsigned*)(hb + (long)sb_ * HID + ch0);
        unsigned hc = *(const unsigned*)(hb + (long)sc_ * HID + ch0);
        unsigned hd = *(const unsigned*)(hb + (long)sd_ * HID + ch0);
        a0 += fmaxf(b2f((ushort_t)(ha & 0xffff)) + b2f((ushort_t)(ga & 0xffff)), 0.f);
        a1 += fmaxf(b2f((ushort_t)(ha >> 16)) + b2f((ushort_t)(ga >> 16)), 0.f);
        a0 += fmaxf(b2f((ushort_t)(hbv & 0xffff)) + b2f((ushort_t)(gb & 0xffff)), 0.f);
        a1 += fmaxf(b2f((ushort_t)(hbv >> 16)) + b2f((ushort_t)(gb >> 16)), 0.f);
        a0 += fmaxf(b2f((ushort_t)(hc & 0xffff)) + b2f((ushort_t)(gc & 0xffff)), 0.f);
        a1 += fmaxf(b2f((ushort_t)(hc >> 16)) + b2f((ushort_t)(gc >> 16)), 0.f);
        a0 += fmaxf(b2f((ushort_t)(hd & 0xffff)) + b2f((ushort_t)(gd & 0xffff)), 0.f);
        a1 += fmaxf(b2f((ushort_t)(hd >> 16)) + b2f((ushort_t)(gd >> 16)), 0.f);
    }
    for (; i < e_hi; ++i) {
        long eg = (long)(i - ce0);
        int s = src_s[i];
        unsigned gv = *(const unsigned*)(g + eg * HID + ch0);
        unsigned hv = *(const unsigned*)(hb + (long)s * HID + ch0);
        a0 += fmaxf(b2f((ushort_t)(hv & 0xffff)) + b2f((ushort_t)(gv & 0xffff)), 0.f);
        a1 += fmaxf(b2f((ushort_t)(hv >> 16)) + b2f((ushort_t)(gv >> 16)), 0.f);
    }
    if (!first) {
        f32x2 p = *(const f32x2*)(zacc + (long)node * HID + ch0);
        a0 += p[0]; a1 += p[1];
    }
    if (last) {
        float ep1 = 1.f + epsv[l];
        f32x2 hn = *(const f32x2*)(h + (long)node * HID + ch0);
        unsigned zz = (unsigned)f2b(fmaf(ep1, hn[0], a0)) |
                      ((unsigned)f2b(fmaf(ep1, hn[1], a1)) << 16);
        *(unsigned*)(z + (long)node * HID + ch0) = zz;
    } else {
        *(f32x2*)(zacc + (long)node * HID + ch0) = (f32x2){a0, a1};
    }
}

// ---------------- mlp1: persistent grid 512, N-split halves, 32KB LDS, A-prefetch ----
__global__ __launch_bounds__(256, 4) void k_mlp1(const ushort_t* __restrict__ z,
                                                 const ushort_t* __restrict__ w1T,
                                                 const float* __restrict__ b1,
                                                 ushort_t* __restrict__ ibuf, int l) {
    __shared__ __align__(16) short lB[128 * HID];  // 32KB [n-half=128][k=128]
    int half = blockIdx.x & 1;
    int mg = blockIdx.x >> 1;  // [0,256)
    const ushort_t* wl = w1T + (long)l * HID2 * HID + (long)half * 128 * HID;
    for (int c = threadIdx.x; c < 128 * HID / 8; c += 256) {
        int row = c >> 4, k0 = (c & 15) * 8;
        short8 v = *(const short8*)(wl + row * HID + k0);
        int g = (k0 >> 3) ^ (row & 7);
        *(short8*)&lB[row * HID + g * 8] = v;
    }
    __syncthreads();
    int wv = threadIdx.x >> 6, l6 = threadIdx.x & 63;
    int lr = l6 & 15, lg = l6 >> 4;
    const float* b1l = b1 + l * HID2 + half * 128;
    int tile = mg;
    short8 a[4];
    {
        const ushort_t* zrow = z + (long)(tile * 64 + wv * 16 + lr) * HID;
#pragma unroll
        for (int kt = 0; kt < 4; ++kt) a[kt] = *(const short8*)(zrow + kt * 32 + lg * 8);
    }
    while (tile < MTILES) {
        int ntile = tile + 256;
        short8 an[4];
        if (ntile < MTILES) {
            const ushort_t* zr2 = z + (long)(ntile * 64 + wv * 16 + lr) * HID;
#pragma unroll
            for (int kt = 0; kt < 4; ++kt) an[kt] = *(const short8*)(zr2 + kt * 32 + lg * 8);
        }
        f32x4 acc[8];
#pragma unroll
        for (int nt = 0; nt < 8; ++nt) acc[nt] = (f32x4){0.f, 0.f, 0.f, 0.f};
#pragma unroll
        for (int kt = 0; kt < 4; ++kt) {
#pragma unroll
            for (int nt = 0; nt < 8; ++nt) {
                int brow = nt * 16 + lr;
                short8 b = *(const short8*)&lB[brow * HID + (((kt * 4 + lg) ^ (brow & 7)) << 3)];
                acc[nt] = __builtin_amdgcn_mfma_f32_16x16x32_bf16(a[kt], b, acc[nt], 0, 0, 0);
            }
        }
        int orow0 = tile * 64 + wv * 16 + lg * 4;
#pragma unroll
        for (int nt = 0; nt < 8; ++nt) {
            int col = half * 128 + nt * 16 + lr;
            float bias = b1l[nt * 16 + lr];
#pragma unroll
            for (int r = 0; r < 4; ++r)
                ibuf[(long)(orow0 + r) * HID2 + col] = f2b(fmaxf(acc[nt][r] + bias, 0.f));
        }
        tile = ntile;
#pragma unroll
        for (int kt = 0; kt < 4; ++kt) a[kt] = an[kt];
    }
}

// ---------------- mlp2: persistent grid 512, N-split halves, 32KB LDS, A-prefetch ----
__global__ __launch_bounds__(256, 4) void k_mlp2(const ushort_t* __restrict__ ibuf,
                                                 const ushort_t* __restrict__ w2T,
                                                 const float* __restrict__ b2,
                                                 ushort_t* __restrict__ z2,
                                                 float* __restrict__ bnstats, int l) {
    __shared__ __align__(16) short lB[64 * HID2];  // 32KB [n-half=64][k=256]
    int half = blockIdx.x & 1;
    int mg = blockIdx.x >> 1;  // [0,256)
    const ushort_t* wl = w2T + (long)l * HID * HID2 + (long)half * 64 * HID2;
    for (int c = threadIdx.x; c < 64 * HID2 / 8; c += 256) {
        int row = c >> 5, k0 = (c & 31) * 8;
        short8 v = *(const short8*)(wl + row * HID2 + k0);
        int g = (k0 >> 3) ^ (row & 7);
        *(short8*)&lB[row * HID2 + g * 8] = v;
    }
    __syncthreads();
    int wv = threadIdx.x >> 6, l6 = threadIdx.x & 63;
    int lr = l6 & 15, lg = l6 >> 4;
    float bS[4] = {0.f, 0.f, 0.f, 0.f}, bQ[4] = {0.f, 0.f, 0.f, 0.f};
    float bias[4];
#pragma unroll
    for (int nt = 0; nt < 4; ++nt) bias[nt] = b2[l * HID + half * 64 + nt * 16 + lr];
    int tile = mg;
    short8 a[8];
    {
        const ushort_t* irow = ibuf + (long)(tile * 64 + wv * 16 + lr) * HID2;
#pragma unroll
        for (int kt = 0; kt < 8; ++kt) a[kt] = *(const short8*)(irow + kt * 32 + lg * 8);
    }
    while (tile < MTILES) {
        int ntile = tile + 256;
        short8 an[8];
        if (ntile < MTILES) {
            const ushort_t* ir2 = ibuf + (long)(ntile * 64 + wv * 16 + lr) * HID2;
#pragma unroll
            for (int kt = 0; kt < 8; ++kt) an[kt] = *(const short8*)(ir2 + kt * 32 + lg * 8);
        }
        f32x4 acc[4];
#pragma unroll
        for (int nt = 0; nt < 4; ++nt) acc[nt] = (f32x4){0.f, 0.f, 0.f, 0.f};
#pragma unroll
        for (int kt = 0; kt < 8; ++kt) {
#pragma unroll
            for (int nt = 0; nt < 4; ++nt) {
                int brow = nt * 16 + lr;
                short8 b = *(const short8*)&lB[brow * HID2 + (((kt * 4 + lg) ^ (brow & 7)) << 3)];
                acc[nt] = __builtin_amdgcn_mfma_f32_16x16x32_bf16(a[kt], b, acc[nt], 0, 0, 0);
            }
        }
        int orow0 = tile * 64 + wv * 16 + lg * 4;
#pragma unroll
        for (int nt = 0; nt < 4; ++nt) {
            int col = half * 64 + nt * 16 + lr;
#pragma unroll
            for (int r = 0; r < 4; ++r) {
                int row = orow0 + r;
                float v = acc[nt][r] + bias[nt];
                if (row < N_NODES) {
                    z2[(long)row * HID + col] = f2b(v);
                    bS[nt] += v;
                    bQ[nt] += v * v;
                }
            }
        }
        tile = ntile;
#pragma unroll
        for (int kt = 0; kt < 8; ++kt) a[kt] = an[kt];
    }
#pragma unroll
    for (int nt = 0; nt < 4; ++nt) {
        float s = bS[nt], q = bQ[nt];
        s += __shfl_xor(s, 16); s += __shfl_xor(s, 32);
        q += __shfl_xor(q, 16); q += __shfl_xor(q, 32);
        if (lg == 0) {
            int col = half * 64 + nt * 16 + lr;
            atomicAdd(&bnstats[l * HID + col], s);
            atomicAdd(&bnstats[(NLAYER + l) * HID + col], q);
        }
    }
}

// ---------------- BN apply + residual + relu: h(f32,bf16) = relu(z2*A + B + h) -------
__global__ __launch_bounds__(1024) void k_resid(const ushort_t* __restrict__ z2,
                                                const float* __restrict__ bnstats,
                                                const float* __restrict__ bng,
                                                const float* __restrict__ bnb,
                                                float* __restrict__ h,
                                                ushort_t* __restrict__ hb, int l) {
    long i = (long)blockIdx.x * 1024 + threadIdx.x;  // grid covers N_NODES*HID exactly
    int c = (int)(i & (HID - 1));
    float inv = 1.f / (float)N_NODES;
    float mu = bnstats[l * HID + c] * inv;
    float var = bnstats[(NLAYER + l) * HID + c] * inv - mu * mu;
    float A = rsqrtf(var + 1e-5f) * bng[l * HID + c];
    float B = bnb[l * HID + c] - mu * A;
    float v = fmaf(b2f(z2[i]), A, B) + h[i];
    v = fmaxf(v, 0.f);
    h[i] = v;
    hb[i] = f2b(v);
}

// ---------------- pooling ----------------
__global__ void k_gstart(const int* __restrict__ batch, int* __restrict__ gstart) {
    int g = threadIdx.x;
    if (g > NGRAPH) return;
    int lo = 0, hi = N_NODES;
    while (lo < hi) { int mid = (lo + hi) >> 1; if (batch[mid] < g) lo = mid + 1; else hi = mid; }
    gstart[g] = lo;
}

__global__ __launch_bounds__(512) void k_pool(const float* __restrict__ h,
                                              const int* __restrict__ gstart,
                                              float* __restrict__ pooled,
                                              float* __restrict__ outp) {
    __shared__ float red[4][HID];
    int g = blockIdx.x;
    int ch = threadIdx.x & 127, seg = threadIdx.x >> 7;
    int st = gstart[g], en = gstart[g + 1];
    float s = 0.f;
    for (int i = st + seg; i < en; i += 4) s += h[(long)i * HID + ch];
    red[seg][ch] = s;
    __syncthreads();
    if (seg == 0) {
        float p = (red[0][ch] + red[1][ch] + red[2][ch] + red[3][ch]) /
                  fmaxf((float)(en - st), 1.f);
        pooled[g * HID + ch] = p;
        outp[g * HID + ch] = p;
    }
}

// ---------------- output MLP ----------------
__global__ __launch_bounds__(128) void k_outmlp(const float* __restrict__ pooled,
                                                const float* __restrict__ w1,
                                                const float* __restrict__ b1,
                                                const float* __restrict__ w2,
                                                const float* __restrict__ b2,
                                                float* __restrict__ outl) {
    __shared__ float pr[HID];
    __shared__ float hid[64];
    int g = blockIdx.x, t = threadIdx.x;
    pr[t] = pooled[g * HID + t];
    __syncthreads();
    if (t < 64) {
        float a = b1[t];
        for (int k = 0; k < HID; ++k) a = fmaf(pr[k], w1[k * 64 + t], a);
        hid[t] = fmaxf(a, 0.f);
    }
    __syncthreads();
    float a = b2[t];
#pragma unroll
    for (int j = 0; j < 64; ++j) a = fmaf(hid[j], w2[j * HID + t], a);
    outl[g * HID + t] = a;
}

// =====================================================================================
extern "C" void kernel_launch(void* const* d_in, const int* in_sizes, int n_in,
                              void* d_out, int out_size, void* d_ws, size_t ws_size,
                              hipStream_t stream) {
    (void)in_sizes; (void)n_in; (void)out_size;
    const float* x      = (const float*)d_in[0];
    const int*   ei     = (const int*)d_in[1];
    const float* ea     = (const float*)d_in[2];
    const int*   batch  = (const int*)d_in[3];
    const float* node_w = (const float*)d_in[4];
    const float* node_b = (const float*)d_in[5];
    const float* edge_w = (const float*)d_in[6];
    const float* edge_b = (const float*)d_in[7];
    const float* epsv   = (const float*)d_in[8];
    const float* lin_w  = (const float*)d_in[9];
    const float* lin_b  = (const float*)d_in[10];
    const float* m1w    = (const float*)d_in[11];
    const float* m1b    = (const float*)d_in[12];
    const float* m2w    = (const float*)d_in[13];
    const float* m2b    = (const float*)d_in[14];
    const float* bng    = (const float*)d_in[15];
    const float* bnb    = (const float*)d_in[16];
    const float* ow1    = (const float*)d_in[17];
    const float* ob1    = (const float*)d_in[18];
    const float* ow2    = (const float*)d_in[19];
    const float* ob2    = (const float*)d_in[20];

    // chunk count for the edge-message buffer g, chosen from ws_size (deterministic)
    const size_t MiB = 1024ull * 1024ull;
    int NC;
    if      (ws_size >= 275 * MiB) NC = 1;
    else if (ws_size >= 193 * MiB) NC = 2;
    else if (ws_size >= 152 * MiB) NC = 4;
    else                           NC = 8;
    int EC = (N_EDGES + NC - 1) / NC;

    char* ws = (char*)d_ws;
    size_t off = 0;
    auto alloc = [&](size_t bytes) -> char* {
        char* p = ws + off;
        off = (off + bytes + 255) & ~(size_t)255;
        return p;
    };
    float*    h       = (float*)alloc((size_t)NPAD * HID * 4);
    ushort_t* hb      = (ushort_t*)alloc((size_t)NPAD * HID * 2);
    ushort_t* z       = (ushort_t*)alloc((size_t)NPAD * HID * 2);   // also reused as z2
    ushort_t* ibuf    = (ushort_t*)alloc((size_t)NPAD * HID2 * 2);  // also aliased as zacc
    ushort_t* ea_sb   = (ushort_t*)alloc((size_t)N_EDGES * EDGE_DIM * 2 + 64);
    ushort_t* g       = (ushort_t*)alloc((size_t)EC * HID * 2);
    int*      src_s   = (int*)alloc((size_t)N_EDGES * 4);
    int*      deg     = (int*)alloc((size_t)N_NODES * 4);
    int*      offs    = (int*)alloc((size_t)N_NODES * 4);
    int*      cursor  = (int*)alloc((size_t)N_NODES * 4);
    int*      bsum    = (int*)alloc(64 * 4);
    ushort_t* WcbT    = (ushort_t*)alloc((size_t)NLAYER * HID * 32 * 2);
    float*    cc      = (float*)alloc((size_t)NLAYER * HID * 4);
    ushort_t* w0T     = (ushort_t*)alloc((size_t)HID * IN_CH * 2);
    ushort_t* w1T     = (ushort_t*)alloc((size_t)NLAYER * HID2 * HID * 2);
    ushort_t* w2T     = (ushort_t*)alloc((size_t)NLAYER * HID * HID2 * 2);
    float*    bnstats = (float*)alloc((size_t)2 * NLAYER * HID * 4);
    int*      gstart  = (int*)alloc((NGRAPH + 1) * 4);
    float*    pooled  = (float*)alloc((size_t)NGRAPH * HID * 4);
    float*    zacc    = (float*)ibuf;
    ushort_t* z2      = z;

    (void)hipMemsetAsync(deg, 0, (size_t)N_NODES * 4, stream);
    (void)hipMemsetAsync(cursor, 0, (size_t)N_NODES * 4, stream);
    (void)hipMemsetAsync(bnstats, 0, (size_t)2 * NLAYER * HID * 4, stream);

    k_transpose_cvt<<<64, 256, 0, stream>>>(node_w, w0T, 1, IN_CH, HID);
    k_transpose_cvt<<<640, 256, 0, stream>>>(m1w, w1T, NLAYER, HID, HID2);
    k_transpose_cvt<<<640, 256, 0, stream>>>(m2w, w2T, NLAYER, HID2, HID);
    k_combine<<<NLAYER, HID, 0, stream>>>(edge_w, edge_b, lin_w, lin_b, WcbT, cc);

    k_hist<<<N_EDGES / 256, 256, 0, stream>>>(ei, deg);
    k_scan1<<<49, 1024, 0, stream>>>(deg, offs, bsum);
    k_scan2<<<1, 1, 0, stream>>>(bsum, 49);
    k_scan3<<<49, 1024, 0, stream>>>(offs, bsum);
    k_scatter<<<N_EDGES / 256, 256, 0, stream>>>(ei, ea, offs, cursor, src_s, ea_sb);

    k_node_enc<<<NPAD / 64, 256, 0, stream>>>(x, w0T, node_b, h, hb);

    for (int l = 0; l < NLAYER; ++l) {
        for (int c = 0; c < NC; ++c) {
            int ce0 = c * EC;
            int ce1 = (ce0 + EC < N_EDGES) ? (ce0 + EC) : N_EDGES;
            int nblk = (ce1 - ce0 + 255) / 256;
            int mode = (c == 0 ? 1 : 0) | (c == NC - 1 ? 2 : 0);
            k_edgegemm<<<nblk, 256, 0, stream>>>(ea_sb, WcbT, cc, g, l, ce0, ce1);
            k_edge2<<<(N_NODES + 3) / 4, 256, 0, stream>>>(g, src_s, offs, deg, h, hb,
                                                           epsv, zacc, z, l, ce0, ce1, mode);
        }
        k_mlp1<<<512, 256, 0, stream>>>(z, w1T, m1b, ibuf, l);
        k_mlp2<<<512, 256, 0, stream>>>(ibuf, w2T, m2b, z2, bnstats, l);
        k_resid<<<(N_NODES * HID) / 1024, 1024, 0, stream>>>(z2, bnstats, bng, bnb, h, hb, l);
    }

    k_gstart<<<1, 256, 0, stream>>>(batch, gstart);
    k_pool<<<NGRAPH, 512, 0, stream>>>(h, gstart, pooled, (float*)d_out + NGRAPH * HID);
    k_outmlp<<<NGRAPH, HID, 0, stream>>>(pooled, ow1, ob1, ow2, ob2, (float*)d_out);
}

// Round 9
// 1361.156 us; speedup vs baseline: 1.5619x; 1.0662x over previous
//
#include <hip/hip_runtime.h>

#define N_NODES  50000
#define NPAD     50048
#define N_EDGES  640000
#define IN_CH    64
#define EDGE_DIM 16
#define HID      128
#define HID2     256
#define NLAYER   5
#define NGRAPH   128
#define RTILES   (NPAD / 16)

typedef unsigned short ushort_t;
typedef __attribute__((ext_vector_type(8))) short short8;
typedef __attribute__((ext_vector_type(4))) short s16x4;
typedef __attribute__((ext_vector_type(4))) float f32x4;
typedef __attribute__((ext_vector_type(2))) float f32x2;

__device__ __forceinline__ float b2f(ushort_t u) {
    union { unsigned v; float f; } x; x.v = ((unsigned)u) << 16; return x.f;
}
__device__ __forceinline__ ushort_t f2b(float f) {
    union { float f; unsigned u; } x; x.f = f;
    unsigned u = x.u;
    unsigned r = (u + 0x7FFFu + ((u >> 16) & 1u)) >> 16;
    return (ushort_t)r;
}

// ---------------- prep: transpose + f32->bf16 convert ----------------
__global__ void k_transpose_cvt(const float* __restrict__ src, ushort_t* __restrict__ dst,
                                int B, int K, int Nn) {
    long total = (long)B * K * Nn;
    for (long i = (long)blockIdx.x * blockDim.x + threadIdx.x; i < total;
         i += (long)gridDim.x * blockDim.x) {
        int b = (int)(i / ((long)K * Nn));
        int rem = (int)(i - (long)b * K * Nn);
        int k = rem / Nn;
        int n = rem - k * Nn;
        dst[(long)b * K * Nn + (long)n * K + k] = f2b(src[i]);
    }
}

// WcbT bf16 [l][col=128][k=32 zero-padded] + cc f32
__global__ __launch_bounds__(128) void k_combine(const float* __restrict__ ew,
                                                 const float* __restrict__ eb,
                                                 const float* __restrict__ lw,
                                                 const float* __restrict__ lb,
                                                 ushort_t* __restrict__ WcbT,
                                                 float* __restrict__ cc) {
    int l = blockIdx.x, j = threadIdx.x;
    float accW[EDGE_DIM];
#pragma unroll
    for (int k = 0; k < EDGE_DIM; ++k) accW[k] = 0.f;
    float accc = 0.f;
    for (int i = 0; i < HID; ++i) {
        float lwv = lw[((long)l * HID + i) * HID + j];
        accc = fmaf(eb[i], lwv, accc);
#pragma unroll
        for (int k = 0; k < EDGE_DIM; ++k)
            accW[k] = fmaf(ew[k * HID + i], lwv, accW[k]);
    }
    ushort_t* wp = WcbT + ((long)l * HID + j) * 32;
#pragma unroll
    for (int k = 0; k < EDGE_DIM; ++k) wp[k] = f2b(accW[k]);
#pragma unroll
    for (int k = EDGE_DIM; k < 32; ++k) wp[k] = 0;
    cc[l * HID + j] = accc + lb[l * HID + j];
}

// ---------------- CSR build ----------------
__global__ __launch_bounds__(256) void k_hist(const int* __restrict__ ei, int* __restrict__ deg) {
    int e = blockIdx.x * 256 + threadIdx.x;
    if (e < N_EDGES) atomicAdd(&deg[ei[N_EDGES + e]], 1);
}

__global__ __launch_bounds__(1024) void k_scan1(const int* __restrict__ deg,
                                                int* __restrict__ offs, int* __restrict__ bsum) {
    __shared__ int s[1024];
    int i = blockIdx.x * 1024 + threadIdx.x;
    int v = (i < N_NODES) ? deg[i] : 0;
    s[threadIdx.x] = v;
    __syncthreads();
    for (int off = 1; off < 1024; off <<= 1) {
        int t = (threadIdx.x >= off) ? s[threadIdx.x - off] : 0;
        __syncthreads();
        s[threadIdx.x] += t;
        __syncthreads();
    }
    if (i < N_NODES) offs[i] = s[threadIdx.x] - v;  // exclusive
    if (threadIdx.x == 1023) bsum[blockIdx.x] = s[1023];
}

__global__ void k_scan2(int* __restrict__ bsum, int nb) {
    if (threadIdx.x == 0 && blockIdx.x == 0) {
        int acc = 0;
        for (int i = 0; i < nb; ++i) { int v = bsum[i]; bsum[i] = acc; acc += v; }
    }
}

__global__ __launch_bounds__(1024) void k_scan3(int* __restrict__ offs, const int* __restrict__ bsum) {
    int i = blockIdx.x * 1024 + threadIdx.x;
    if (i < N_NODES) offs[i] += bsum[blockIdx.x];
}

__global__ __launch_bounds__(256) void k_scatter(const int* __restrict__ ei,
                                                 const float* __restrict__ ea,
                                                 const int* __restrict__ offs,
                                                 int* __restrict__ cursor,
                                                 int* __restrict__ src_s,
                                                 ushort_t* __restrict__ ea_sb) {
    int e = blockIdx.x * 256 + threadIdx.x;
    if (e >= N_EDGES) return;
    int d = ei[N_EDGES + e];
    int pos = offs[d] + atomicAdd(&cursor[d], 1);
    src_s[pos] = ei[e];
    const f32x4* srcp = (const f32x4*)(ea + (long)e * EDGE_DIM);
    f32x4 v0 = srcp[0], v1 = srcp[1], v2 = srcp[2], v3 = srcp[3];
    short8 o0, o1;
#pragma unroll
    for (int j = 0; j < 4; ++j) {
        o0[j] = (short)f2b(v0[j]); o0[4 + j] = (short)f2b(v1[j]);
        o1[j] = (short)f2b(v2[j]); o1[4 + j] = (short)f2b(v3[j]);
    }
    short8* dst = (short8*)(ea_sb + (long)pos * EDGE_DIM);
    dst[0] = o0;
    dst[1] = o1;
}

// ---------------- node encoder: h = relu(x @ node_w + node_b), f32 + bf16 out --------
__global__ __launch_bounds__(256) void k_node_enc(const float* __restrict__ x,
                                                  const ushort_t* __restrict__ w0T,
                                                  const float* __restrict__ nb,
                                                  float* __restrict__ h,
                                                  ushort_t* __restrict__ hb) {
    __shared__ __align__(16) short lB[HID * IN_CH];
    for (int c = threadIdx.x; c < HID * IN_CH / 8; c += 256) {
        int row = c >> 3, k0 = (c & 7) * 8;
        short8 v = *(const short8*)(w0T + row * IN_CH + k0);
        int g = (k0 >> 3) ^ (row & 7);
        *(short8*)&lB[row * IN_CH + g * 8] = v;
    }
    __syncthreads();
    int wv = threadIdx.x >> 6, l6 = threadIdx.x & 63;
    int lr = l6 & 15, lg = l6 >> 4;
    int grow = blockIdx.x * 64 + wv * 16 + lr;
    f32x4 acc[8];
#pragma unroll
    for (int nt = 0; nt < 8; ++nt) acc[nt] = (f32x4){0.f, 0.f, 0.f, 0.f};
#pragma unroll
    for (int kt = 0; kt < 2; ++kt) {
        int kk = kt * 32 + lg * 8;
        short8 a = {0, 0, 0, 0, 0, 0, 0, 0};
        if (grow < N_NODES) {
            const float* xr = x + (long)grow * IN_CH + kk;
            f32x4 v0 = *(const f32x4*)xr;
            f32x4 v1 = *(const f32x4*)(xr + 4);
#pragma unroll
            for (int j = 0; j < 4; ++j) { a[j] = (short)f2b(v0[j]); a[4 + j] = (short)f2b(v1[j]); }
        }
#pragma unroll
        for (int nt = 0; nt < 8; ++nt) {
            int brow = nt * 16 + lr;
            short8 b = *(const short8*)&lB[brow * IN_CH + (((kk >> 3) ^ (brow & 7)) << 3)];
            acc[nt] = __builtin_amdgcn_mfma_f32_16x16x32_bf16(a, b, acc[nt], 0, 0, 0);
        }
    }
    int orow0 = blockIdx.x * 64 + wv * 16 + lg * 4;
#pragma unroll
    for (int nt = 0; nt < 8; ++nt) {
        int col = nt * 16 + lr;
        float bias = nb[col];
#pragma unroll
        for (int r = 0; r < 4; ++r) {
            int row = orow0 + r;
            if (row < N_NODES) {
                float v = fmaxf(acc[nt][r] + bias, 0.f);
                h[(long)row * HID + col] = v;
                hb[(long)row * HID + col] = f2b(v);
            }
        }
    }
}

// ---------------- per-layer edge GEMM (chunk [ce0,ce1)) ----------------
__global__ __launch_bounds__(256) void k_edgegemm(const ushort_t* __restrict__ ea_sb,
                                                  const ushort_t* __restrict__ WcbT,
                                                  const float* __restrict__ cc,
                                                  ushort_t* __restrict__ g, int l,
                                                  int ce0, int ce1) {
    int wv = threadIdx.x >> 6, l6 = threadIdx.x & 63;
    int lr = l6 & 15, lg = l6 >> 4;
    short8 af[8];
    f32x4 cv[8];
    const ushort_t* wp = WcbT + (long)l * HID * 32;
#pragma unroll
    for (int nt = 0; nt < 8; ++nt) {
        af[nt] = *(const short8*)(wp + (nt * 16 + lr) * 32 + lg * 8);
        cv[nt] = *(const f32x4*)(cc + l * HID + nt * 16 + lg * 4);
    }
    for (int it = 0; it < 4; ++it) {
        int e0 = ce0 + blockIdx.x * 256 + wv * 64 + it * 16;
        int e = e0 + lr;
        short8 b = {0, 0, 0, 0, 0, 0, 0, 0};
        if (e < ce1 && lg < 2) b = *(const short8*)(ea_sb + (long)e * EDGE_DIM + lg * 8);
        f32x4 acc[8];
#pragma unroll
        for (int nt = 0; nt < 8; ++nt) acc[nt] = (f32x4){0.f, 0.f, 0.f, 0.f};
#pragma unroll
        for (int nt = 0; nt < 8; ++nt)
            acc[nt] = __builtin_amdgcn_mfma_f32_16x16x32_bf16(af[nt], b, acc[nt], 0, 0, 0);
        if (e < ce1) {
            ushort_t* gp = g + (long)(e - ce0) * HID + lg * 4;
#pragma unroll
            for (int nt = 0; nt < 8; ++nt) {
                s16x4 o;
#pragma unroll
                for (int r = 0; r < 4; ++r) o[r] = (short)f2b(acc[nt][r] + cv[nt][r]);
                *(s16x4*)(gp + nt * 16) = o;
            }
        }
    }
}

// ---------------- per-layer aggregation over chunk [ce0,ce1) ----------------
__global__ __launch_bounds__(256) void k_edge2(const ushort_t* __restrict__ g,
                                               const int* __restrict__ src_s,
                                               const int* __restrict__ offs,
                                               const int* __restrict__ deg,
                                               const float* __restrict__ h,
                                               const ushort_t* __restrict__ hb,
                                               const float* __restrict__ epsv,
                                               float* __restrict__ zacc,
                                               ushort_t* __restrict__ z,
                                               int l, int ce0, int ce1, int mode) {
    int lane = threadIdx.x & 63;
    int node = blockIdx.x * 4 + (threadIdx.x >> 6);
    if (node >= N_NODES) return;
    bool first = mode & 1, last = (mode & 2) != 0;
    int ch0 = lane * 2;
    int s0 = offs[node];
    int dg = deg[node];
    int e_lo = max(s0, ce0);
    int e_hi = min(s0 + dg, ce1);
    if (e_lo >= e_hi && !first && !last) return;
    float a0 = 0.f, a1 = 0.f;
    int i = e_lo;
    for (; i + 4 <= e_hi; i += 4) {
        long eg = (long)(i - ce0);
        int sa = src_s[i], sb_ = src_s[i + 1], sc_ = src_s[i + 2], sd_ = src_s[i + 3];
        unsigned ga = *(const unsigned*)(g + eg * HID + ch0);
        unsigned gb = *(const unsigned*)(g + (eg + 1) * HID + ch0);
        unsigned gc = *(const unsigned*)(g + (eg + 2) * HID + ch0);
        unsigned gd = *(const unsigned*)(g + (eg + 3) * HID + ch0);
        unsigned ha = *(const unsigned*)(hb + (long)sa * HID + ch0);
        unsigned hbv = *(const unsigned*)(hb + (long)sb_ * HID + ch0);
        unsigned hc = *(const unsigned*)(hb + (long)sc_ * HID + ch0);
        unsigned hd = *(const unsigned*)(hb + (long)sd_ * HID + ch0);
        a0 += fmaxf(b2f((ushort_t)(ha & 0xffff)) + b2f((ushort_t)(ga & 0xffff)), 0.f);
        a1 += fmaxf(b2f((ushort_t)(ha >> 16)) + b2f((ushort_t)(ga >> 16)), 0.f);
        a0 += fmaxf(b2f((ushort_t)(hbv & 0xffff)) + b2f((ushort_t)(gb & 0xffff)), 0.f);
        a1 += fmaxf(b2f((ushort_t)(hbv >> 16)) + b2f((ushort_t)(gb >> 16)), 0.f);
        a0 += fmaxf(b2f((ushort_t)(hc & 0xffff)) + b2f((ushort_t)(gc & 0xffff)), 0.f);
        a1 += fmaxf(b2f((ushort_t)(hc >> 16)) + b2f((ushort_t)(gc >> 16)), 0.f);
        a0 += fmaxf(b2f((ushort_t)(hd & 0xffff)) + b2f((ushort_t)(gd & 0xffff)), 0.f);
        a1 += fmaxf(b2f((ushort_t)(hd >> 16)) + b2f((ushort_t)(gd >> 16)), 0.f);
    }
    for (; i < e_hi; ++i) {
        long eg = (long)(i - ce0);
        int s = src_s[i];
        unsigned gv = *(const unsigned*)(g + eg * HID + ch0);
        unsigned hv = *(const unsigned*)(hb + (long)s * HID + ch0);
        a0 += fmaxf(b2f((ushort_t)(hv & 0xffff)) + b2f((ushort_t)(gv & 0xffff)), 0.f);
        a1 += fmaxf(b2f((ushort_t)(hv >> 16)) + b2f((ushort_t)(gv >> 16)), 0.f);
    }
    if (!first) {
        f32x2 p = *(const f32x2*)(zacc + (long)node * HID + ch0);
        a0 += p[0]; a1 += p[1];
    }
    if (last) {
        float ep1 = 1.f + epsv[l];
        f32x2 hn = *(const f32x2*)(h + (long)node * HID + ch0);
        unsigned zz = (unsigned)f2b(fmaf(ep1, hn[0], a0)) |
                      ((unsigned)f2b(fmaf(ep1, hn[1], a1)) << 16);
        *(unsigned*)(z + (long)node * HID + ch0) = zz;
    } else {
        *(f32x2*)(zacc + (long)node * HID + ch0) = (f32x2){a0, a1};
    }
}

// ---------------- mlp1: weights-in-regs (A-operand), activations as B, packed stores ----
// Wave wv owns out-cols [wv*64, wv*64+64); block grid-strides over 16-row tiles.
__global__ __launch_bounds__(256) void k_mlp1(const ushort_t* __restrict__ z,
                                              const ushort_t* __restrict__ w1T,
                                              const float* __restrict__ b1,
                                              ushort_t* __restrict__ ibuf, int l) {
    int wv = threadIdx.x >> 6, l6 = threadIdx.x & 63;
    int lr = l6 & 15, lg = l6 >> 4;
    const ushort_t* wl = w1T + (long)l * HID2 * HID;
    short8 af[4][4];   // [nt][kt]; out-col row = (wv*4+nt)*16 + lr, k = kt*32 + lg*8
    f32x4  bv[4];
#pragma unroll
    for (int nt = 0; nt < 4; ++nt) {
        int mf = wv * 4 + nt;
#pragma unroll
        for (int kt = 0; kt < 4; ++kt)
            af[nt][kt] = *(const short8*)(wl + (mf * 16 + lr) * HID + kt * 32 + lg * 8);
        bv[nt] = *(const f32x4*)(b1 + l * HID2 + mf * 16 + lg * 4);
    }
    int rt = blockIdx.x;
    short8 b[4];
    {
        const ushort_t* zr = z + (long)(rt * 16 + lr) * HID;
#pragma unroll
        for (int kt = 0; kt < 4; ++kt) b[kt] = *(const short8*)(zr + kt * 32 + lg * 8);
    }
    while (rt < RTILES) {
        int nrt = rt + gridDim.x;
        short8 bn_[4];
        if (nrt < RTILES) {
            const ushort_t* zr = z + (long)(nrt * 16 + lr) * HID;
#pragma unroll
            for (int kt = 0; kt < 4; ++kt) bn_[kt] = *(const short8*)(zr + kt * 32 + lg * 8);
        }
#pragma unroll
        for (int nt = 0; nt < 4; ++nt) {
            f32x4 acc = (f32x4){0.f, 0.f, 0.f, 0.f};
#pragma unroll
            for (int kt = 0; kt < 4; ++kt)
                acc = __builtin_amdgcn_mfma_f32_16x16x32_bf16(af[nt][kt], b[kt], acc, 0, 0, 0);
            // D: lane holds row (z-row) = rt*16 + lr, cols = mf*16 + lg*4 + r
            int mf = wv * 4 + nt;
            s16x4 o;
#pragma unroll
            for (int r = 0; r < 4; ++r) o[r] = (short)f2b(fmaxf(acc[r] + bv[nt][r], 0.f));
            *(s16x4*)(ibuf + (long)(rt * 16 + lr) * HID2 + mf * 16 + lg * 4) = o;
        }
        rt = nrt;
#pragma unroll
        for (int kt = 0; kt < 4; ++kt) b[kt] = bn_[kt];
    }
}

// ---------------- mlp2: weights-in-regs, packed stores, reg BN stats ----------------
// Wave wv owns out-cols [wv*32, wv*32+32).
__global__ __launch_bounds__(256) void k_mlp2(const ushort_t* __restrict__ ibuf,
                                              const ushort_t* __restrict__ w2T,
                                              const float* __restrict__ b2,
                                              ushort_t* __restrict__ z2,
                                              float* __restrict__ bnstats, int l) {
    int wv = threadIdx.x >> 6, l6 = threadIdx.x & 63;
    int lr = l6 & 15, lg = l6 >> 4;
    const ushort_t* wl = w2T + (long)l * HID * HID2;
    short8 af[2][8];   // [nt][kt]; out-col = (wv*2+nt)*16 + lr rows, k = kt*32 + lg*8
    f32x4  bv[2];
#pragma unroll
    for (int nt = 0; nt < 2; ++nt) {
        int mf = wv * 2 + nt;
#pragma unroll
        for (int kt = 0; kt < 8; ++kt)
            af[nt][kt] = *(const short8*)(wl + (mf * 16 + lr) * HID2 + kt * 32 + lg * 8);
        bv[nt] = *(const f32x4*)(b2 + l * HID + mf * 16 + lg * 4);
    }
    float bS[2][4] = {{0.f, 0.f, 0.f, 0.f}, {0.f, 0.f, 0.f, 0.f}};
    float bQ[2][4] = {{0.f, 0.f, 0.f, 0.f}, {0.f, 0.f, 0.f, 0.f}};
    int rt = blockIdx.x;
    short8 b[8];
    {
        const ushort_t* ir = ibuf + (long)(rt * 16 + lr) * HID2;
#pragma unroll
        for (int kt = 0; kt < 8; ++kt) b[kt] = *(const short8*)(ir + kt * 32 + lg * 8);
    }
    while (rt < RTILES) {
        int nrt = rt + gridDim.x;
        short8 bn_[8];
        if (nrt < RTILES) {
            const ushort_t* ir = ibuf + (long)(nrt * 16 + lr) * HID2;
#pragma unroll
            for (int kt = 0; kt < 8; ++kt) bn_[kt] = *(const short8*)(ir + kt * 32 + lg * 8);
        }
        int zrow = rt * 16 + lr;
        bool valid = zrow < N_NODES;
#pragma unroll
        for (int nt = 0; nt < 2; ++nt) {
            f32x4 acc = (f32x4){0.f, 0.f, 0.f, 0.f};
#pragma unroll
            for (int kt = 0; kt < 8; ++kt)
                acc = __builtin_amdgcn_mfma_f32_16x16x32_bf16(af[nt][kt], b[kt], acc, 0, 0, 0);
            int mf = wv * 2 + nt;
            s16x4 o;
#pragma unroll
            for (int r = 0; r < 4; ++r) {
                float v = acc[r] + bv[nt][r];
                o[r] = (short)f2b(v);
                if (valid) { bS[nt][r] += v; bQ[nt][r] += v * v; }
            }
            *(s16x4*)(z2 + (long)zrow * HID + mf * 16 + lg * 4) = o;
        }
        rt = nrt;
#pragma unroll
        for (int kt = 0; kt < 8; ++kt) b[kt] = bn_[kt];
    }
    // reduce over lr (lane bits 0..3) -> per-column sums, one atomic per col per wave
#pragma unroll
    for (int nt = 0; nt < 2; ++nt) {
#pragma unroll
        for (int r = 0; r < 4; ++r) {
            float s = bS[nt][r], q = bQ[nt][r];
            s += __shfl_xor(s, 1); s += __shfl_xor(s, 2);
            s += __shfl_xor(s, 4); s += __shfl_xor(s, 8);
            q += __shfl_xor(q, 1); q += __shfl_xor(q, 2);
            q += __shfl_xor(q, 4); q += __shfl_xor(q, 8);
            if (lr == 0) {
                int col = (wv * 2 + nt) * 16 + lg * 4 + r;
                atomicAdd(&bnstats[l * HID + col], s);
                atomicAdd(&bnstats[(NLAYER + l) * HID + col], q);
            }
        }
    }
}

// ---------------- BN apply + residual + relu ----------------
__global__ __launch_bounds__(1024) void k_resid(const ushort_t* __restrict__ z2,
                                                const float* __restrict__ bnstats,
                                                const float* __restrict__ bng,
                                                const float* __restrict__ bnb,
                                                float* __restrict__ h,
                                                ushort_t* __restrict__ hb, int l) {
    long i = (long)blockIdx.x * 1024 + threadIdx.x;
    int c = (int)(i & (HID - 1));
    float inv = 1.f / (float)N_NODES;
    float mu = bnstats[l * HID + c] * inv;
    float var = bnstats[(NLAYER + l) * HID + c] * inv - mu * mu;
    float A = rsqrtf(var + 1e-5f) * bng[l * HID + c];
    float B = bnb[l * HID + c] - mu * A;
    float v = fmaf(b2f(z2[i]), A, B) + h[i];
    v = fmaxf(v, 0.f);
    h[i] = v;
    hb[i] = f2b(v);
}

// ---------------- pooling ----------------
__global__ void k_gstart(const int* __restrict__ batch, int* __restrict__ gstart) {
    int g = threadIdx.x;
    if (g > NGRAPH) return;
    int lo = 0, hi = N_NODES;
    while (lo < hi) { int mid = (lo + hi) >> 1; if (batch[mid] < g) lo = mid + 1; else hi = mid; }
    gstart[g] = lo;
}

__global__ __launch_bounds__(512) void k_pool(const float* __restrict__ h,
                                              const int* __restrict__ gstart,
                                              float* __restrict__ pooled,
                                              float* __restrict__ outp) {
    __shared__ float red[4][HID];
    int g = blockIdx.x;
    int ch = threadIdx.x & 127, seg = threadIdx.x >> 7;
    int st = gstart[g], en = gstart[g + 1];
    float s = 0.f;
    for (int i = st + seg; i < en; i += 4) s += h[(long)i * HID + ch];
    red[seg][ch] = s;
    __syncthreads();
    if (seg == 0) {
        float p = (red[0][ch] + red[1][ch] + red[2][ch] + red[3][ch]) /
                  fmaxf((float)(en - st), 1.f);
        pooled[g * HID + ch] = p;
        outp[g * HID + ch] = p;
    }
}

// ---------------- output MLP ----------------
__global__ __launch_bounds__(128) void k_outmlp(const float* __restrict__ pooled,
                                                const float* __restrict__ w1,
                                                const float* __restrict__ b1,
                                                const float* __restrict__ w2,
                                                const float* __restrict__ b2,
                                                float* __restrict__ outl) {
    __shared__ float pr[HID];
    __shared__ float hid[64];
    int g = blockIdx.x, t = threadIdx.x;
    pr[t] = pooled[g * HID + t];
    __syncthreads();
    if (t < 64) {
        float a = b1[t];
        for (int k = 0; k < HID; ++k) a = fmaf(pr[k], w1[k * 64 + t], a);
        hid[t] = fmaxf(a, 0.f);
    }
    __syncthreads();
    float a = b2[t];
#pragma unroll
    for (int j = 0; j < 64; ++j) a = fmaf(hid[j], w2[j * HID + t], a);
    outl[g * HID + t] = a;
}

// =====================================================================================
extern "C" void kernel_launch(void* const* d_in, const int* in_sizes, int n_in,
                              void* d_out, int out_size, void* d_ws, size_t ws_size,
                              hipStream_t stream) {
    (void)in_sizes; (void)n_in; (void)out_size;
    const float* x      = (const float*)d_in[0];
    const int*   ei     = (const int*)d_in[1];
    const float* ea     = (const float*)d_in[2];
    const int*   batch  = (const int*)d_in[3];
    const float* node_w = (const float*)d_in[4];
    const float* node_b = (const float*)d_in[5];
    const float* edge_w = (const float*)d_in[6];
    const float* edge_b = (const float*)d_in[7];
    const float* epsv   = (const float*)d_in[8];
    const float* lin_w  = (const float*)d_in[9];
    const float* lin_b  = (const float*)d_in[10];
    const float* m1w    = (const float*)d_in[11];
    const float* m1b    = (const float*)d_in[12];
    const float* m2w    = (const float*)d_in[13];
    const float* m2b    = (const float*)d_in[14];
    const float* bng    = (const float*)d_in[15];
    const float* bnb    = (const float*)d_in[16];
    const float* ow1    = (const float*)d_in[17];
    const float* ob1    = (const float*)d_in[18];
    const float* ow2    = (const float*)d_in[19];
    const float* ob2    = (const float*)d_in[20];

    const size_t MiB = 1024ull * 1024ull;
    int NC;
    if      (ws_size >= 275 * MiB) NC = 1;
    else if (ws_size >= 193 * MiB) NC = 2;
    else if (ws_size >= 152 * MiB) NC = 4;
    else                           NC = 8;
    int EC = (N_EDGES + NC - 1) / NC;

    char* ws = (char*)d_ws;
    size_t off = 0;
    auto alloc = [&](size_t bytes) -> char* {
        char* p = ws + off;
        off = (off + bytes + 255) & ~(size_t)255;
        return p;
    };
    float*    h       = (float*)alloc((size_t)NPAD * HID * 4);
    ushort_t* hb      = (ushort_t*)alloc((size_t)NPAD * HID * 2);
    ushort_t* z       = (ushort_t*)alloc((size_t)NPAD * HID * 2);   // reused as z2
    ushort_t* ibuf    = (ushort_t*)alloc((size_t)NPAD * HID2 * 2);  // aliased as zacc
    ushort_t* ea_sb   = (ushort_t*)alloc((size_t)N_EDGES * EDGE_DIM * 2 + 64);
    ushort_t* g       = (ushort_t*)alloc((size_t)EC * HID * 2);
    int*      src_s   = (int*)alloc((size_t)N_EDGES * 4);
    int*      deg     = (int*)alloc((size_t)N_NODES * 4);
    int*      offs    = (int*)alloc((size_t)N_NODES * 4);
    int*      cursor  = (int*)alloc((size_t)N_NODES * 4);
    int*      bsum    = (int*)alloc(64 * 4);
    ushort_t* WcbT    = (ushort_t*)alloc((size_t)NLAYER * HID * 32 * 2);
    float*    cc      = (float*)alloc((size_t)NLAYER * HID * 4);
    ushort_t* w0T     = (ushort_t*)alloc((size_t)HID * IN_CH * 2);
    ushort_t* w1T     = (ushort_t*)alloc((size_t)NLAYER * HID2 * HID * 2);
    ushort_t* w2T     = (ushort_t*)alloc((size_t)NLAYER * HID * HID2 * 2);
    float*    bnstats = (float*)alloc((size_t)2 * NLAYER * HID * 4);
    int*      gstart  = (int*)alloc((NGRAPH + 1) * 4);
    float*    pooled  = (float*)alloc((size_t)NGRAPH * HID * 4);
    float*    zacc    = (float*)ibuf;
    ushort_t* z2      = z;

    (void)hipMemsetAsync(deg, 0, (size_t)N_NODES * 4, stream);
    (void)hipMemsetAsync(cursor, 0, (size_t)N_NODES * 4, stream);
    (void)hipMemsetAsync(bnstats, 0, (size_t)2 * NLAYER * HID * 4, stream);

    k_transpose_cvt<<<64, 256, 0, stream>>>(node_w, w0T, 1, IN_CH, HID);
    k_transpose_cvt<<<640, 256, 0, stream>>>(m1w, w1T, NLAYER, HID, HID2);
    k_transpose_cvt<<<640, 256, 0, stream>>>(m2w, w2T, NLAYER, HID2, HID);
    k_combine<<<NLAYER, HID, 0, stream>>>(edge_w, edge_b, lin_w, lin_b, WcbT, cc);

    k_hist<<<N_EDGES / 256, 256, 0, stream>>>(ei, deg);
    k_scan1<<<49, 1024, 0, stream>>>(deg, offs, bsum);
    k_scan2<<<1, 1, 0, stream>>>(bsum, 49);
    k_scan3<<<49, 1024, 0, stream>>>(offs, bsum);
    k_scatter<<<N_EDGES / 256, 256, 0, stream>>>(ei, ea, offs, cursor, src_s, ea_sb);

    k_node_enc<<<NPAD / 64, 256, 0, stream>>>(x, w0T, node_b, h, hb);

    for (int l = 0; l < NLAYER; ++l) {
        for (int c = 0; c < NC; ++c) {
            int ce0 = c * EC;
            int ce1 = (ce0 + EC < N_EDGES) ? (ce0 + EC) : N_EDGES;
            int nblk = (ce1 - ce0 + 255) / 256;
            int mode = (c == 0 ? 1 : 0) | (c == NC - 1 ? 2 : 0);
            k_edgegemm<<<nblk, 256, 0, stream>>>(ea_sb, WcbT, cc, g, l, ce0, ce1);
            k_edge2<<<(N_NODES + 3) / 4, 256, 0, stream>>>(g, src_s, offs, deg, h, hb,
                                                           epsv, zacc, z, l, ce0, ce1, mode);
        }
        k_mlp1<<<1024, 256, 0, stream>>>(z, w1T, m1b, ibuf, l);
        k_mlp2<<<768, 256, 0, stream>>>(ibuf, w2T, m2b, z2, bnstats, l);
        k_resid<<<(N_NODES * HID) / 1024, 1024, 0, stream>>>(z2, bnstats, bng, bnb, h, hb, l);
    }

    k_gstart<<<1, 256, 0, stream>>>(batch, gstart);
    k_pool<<<NGRAPH, 512, 0, stream>>>(h, gstart, pooled, (float*)d_out + NGRAPH * HID);
    k_outmlp<<<NGRAPH, HID, 0, stream>>>(pooled, ow1, ob1, ow2, ob2, (float*)d_out);
}